// Round 4
// baseline (462.841 us; speedup 1.0000x reference)
//
#include <hip/hip_runtime.h>
#include <math.h>

#define BB 8
#define CATP 3584   // padded cat K (3572 -> 3584, zeros)
#define CAT_REAL 3572

typedef __attribute__((ext_vector_type(8))) short short8;
typedef __attribute__((ext_vector_type(4))) float f32x4;

__device__ inline ushort f2bf(float f) {
  union { float f; unsigned u; } x;
  x.f = f;
  return (ushort)((x.u + 0x7FFFu + ((x.u >> 16) & 1u)) >> 16);
}
__device__ inline float bf2f(unsigned us) {
  union { unsigned u; float f; } x;
  x.u = us << 16;
  return x.f;
}

// ---------------------------------------------------------------------------
// f32 -> bf16 elementwise convert (4-wide), n multiple of 4
// ---------------------------------------------------------------------------
__global__ __launch_bounds__(256) void cvt_bf16_kernel(
    const float4* __restrict__ X, uint2* __restrict__ Y, int n4) {
  const int i = blockIdx.x * 256 + threadIdx.x;
  if (i >= n4) return;
  const float4 v = X[i];
  uint2 o;
  o.x = (unsigned)f2bf(v.x) | ((unsigned)f2bf(v.y) << 16);
  o.y = (unsigned)f2bf(v.z) | ((unsigned)f2bf(v.w) << 16);
  Y[i] = o;
}

// w_prop [512][3572] f32 -> [512][3584] bf16 with zero pad
__global__ __launch_bounds__(256) void cvt_pad_wprop_kernel(
    const float* __restrict__ W, unsigned* __restrict__ Y) {
  const int idx = blockIdx.x * 256 + threadIdx.x;
  if (idx >= 512 * (CATP / 2)) return;
  const int p = idx % (CATP / 2);
  const int o = idx / (CATP / 2);
  const int c0 = p * 2;
  unsigned pk = 0;
  if (c0 < CAT_REAL) {
    const float* w = W + (size_t)o * CAT_REAL + c0;
    pk = (unsigned)f2bf(w[0]) | ((unsigned)f2bf(w[1]) << 16);
  }
  Y[(size_t)o * (CATP / 2) + p] = pk;
}

// ---------------------------------------------------------------------------
// Transpose+convert: X f32 [B][C][L] -> Y bf16 rows (b*L+l)*rowStride+chOff+c
// grid (ceil(C/64), L/64, B)
// ---------------------------------------------------------------------------
__global__ __launch_bounds__(256) void transpose_cvt_kernel(
    const float* __restrict__ X, ushort* __restrict__ Y, int C, int L,
    int rowStride, int chOff) {
  __shared__ float tile[64 * 65];
  const int c0 = blockIdx.x * 64;
  const int l0 = blockIdx.y * 64;
  const int b = blockIdx.z;
  for (int e = threadIdx.x; e < 4096; e += 256) {
    const int cc = e >> 6, ll = e & 63;
    const int c = c0 + cc;
    tile[cc * 65 + ll] = (c < C) ? X[((size_t)b * C + c) * L + l0 + ll] : 0.f;
  }
  __syncthreads();
  for (int e = threadIdx.x; e < 4096; e += 256) {
    const int ll = e >> 6, cc = e & 63;
    const int c = c0 + cc;
    if (c < C)
      Y[((size_t)b * L + l0 + ll) * rowStride + chOff + c] =
          f2bf(tile[cc * 65 + ll]);
  }
}

// LocResult [8][2][64] -> cat[3570:3572], plus zero-pad cat[3572:3584]
__global__ __launch_bounds__(256) void locres_pad_kernel(
    const float* __restrict__ L, ushort* __restrict__ cat) {
  const int idx = blockIdx.x * 256 + threadIdx.x;
  if (idx >= BB * 64 * 14) return;
  const int j = idx % 14;
  const int t = (idx / 14) % 64;
  const int b = idx / (14 * 64);
  const ushort v = (j < 2) ? f2bf(L[((size_t)b * 2 + j) * 64 + t]) : (ushort)0;
  cat[((size_t)(b * 64) + t) * CATP + 3570 + j] = v;
}

// ---------------------------------------------------------------------------
// BoundaryMaxPooling on transposed bf16 input Xt [(b*L+l)*C + c].
// Block = (t, b); lanes = channel pairs (both halves flattened so all lanes
// active); coalesced uint loads/stores. grid (64, B).
// ---------------------------------------------------------------------------
template <int C, int L>
__global__ __launch_bounds__(256) void bmp_t_kernel(
    const ushort* __restrict__ Xt, const int* __restrict__ segs,
    ushort* __restrict__ Y, int rowStride, int chOff) {
  const int t = blockIdx.x;
  const int b = blockIdx.y;
  const int* sg = segs + ((size_t)b * 64 + t) * 4;
  constexpr int C2 = C / 2;
  const int s0 = min(max(sg[0], 0), L - 1);
  const int e0 = max(min(max(sg[1], 0), L - 1), s0);
  const int s1 = min(max(sg[2], 0), L - 1);
  const int e1 = max(min(max(sg[3], 0), L - 1), s1);
  for (int p = threadIdx.x; p < C / 2; p += 256) {
    const int c0 = 2 * p;
    const bool h1 = (c0 >= C2);
    const int s = h1 ? s1 : s0;
    const int e = h1 ? e1 : e0;
    float m0 = -INFINITY, m1 = -INFINITY;
    const ushort* base = Xt + (size_t)b * L * C + c0;
    for (int l = s; l <= e; l++) {
      const unsigned u = *(const unsigned*)(base + (size_t)l * C);
      m0 = fmaxf(m0, bf2f(u & 0xffffu));
      m1 = fmaxf(m1, bf2f(u >> 16));
    }
    const unsigned o = (unsigned)f2bf(m0) | ((unsigned)f2bf(m1) << 16);
    *(unsigned*)(Y + ((size_t)(b * 64) + t) * rowStride + chOff + c0) = o;
  }
}

// ---------------------------------------------------------------------------
// Fused bf16 MFMA GEMM + GroupNorm + ReLU.
// Block: (64 o) x (64 t, one b); 4 waves split K; LDS reduce; in-block GN.
// Writes f32 [b][M][64] (outF) and/or bf16 transposed rows (catOut).
// grid (M/64, B).
// ---------------------------------------------------------------------------
__global__ __launch_bounds__(256) void gemm_gn_relu_kernel(
    const ushort* __restrict__ Xt, const ushort* __restrict__ Wb,
    const float* __restrict__ bias, const float* __restrict__ gamma,
    const float* __restrict__ beta, int Kp, int M, int cpgShift,
    float* __restrict__ outF, ushort* __restrict__ catOut, int catStride,
    int chOff) {
  const int o0 = blockIdx.x * 64;
  const int b = blockIdx.y;
  const int w = threadIdx.x >> 6;
  const int lane = threadIdx.x & 63;
  const int l15 = lane & 15, l4 = lane >> 4;
  const int wk = Kp >> 2;
  const int kbeg = w * wk, kend = kbeg + wk;

  f32x4 acc[4][4] = {};
  const ushort* ap[4];
  const ushort* bp[4];
#pragma unroll
  for (int i = 0; i < 4; i++)
    ap[i] = Wb + (size_t)(o0 + i * 16 + l15) * Kp + l4 * 8;
#pragma unroll
  for (int j = 0; j < 4; j++)
    bp[j] = Xt + (size_t)(b * 64 + j * 16 + l15) * Kp + l4 * 8;

  for (int k = kbeg; k < kend; k += 32) {
    short8 a[4], x[4];
#pragma unroll
    for (int i = 0; i < 4; i++) a[i] = *(const short8*)(ap[i] + k);
#pragma unroll
    for (int j = 0; j < 4; j++) x[j] = *(const short8*)(bp[j] + k);
#pragma unroll
    for (int i = 0; i < 4; i++)
#pragma unroll
      for (int j = 0; j < 4; j++)
        acc[i][j] = __builtin_amdgcn_mfma_f32_16x16x32_bf16(a[i], x[j],
                                                            acc[i][j], 0, 0, 0);
  }

  __shared__ float red[64 * 65];
  for (int ww = 0; ww < 4; ww++) {
    __syncthreads();
    if (w == ww) {
#pragma unroll
      for (int i = 0; i < 4; i++)
#pragma unroll
        for (int j = 0; j < 4; j++)
#pragma unroll
          for (int r = 0; r < 4; r++) {
            const int m = i * 16 + l4 * 4 + r;
            const int n = j * 16 + l15;
            if (ww == 0)
              red[m * 65 + n] = acc[i][j][r] + bias[o0 + m];
            else
              red[m * 65 + n] += acc[i][j][r];
          }
    }
  }
  __syncthreads();

  const int cpg = 1 << cpgShift;
  const int ngroups = 64 >> cpgShift;
  __shared__ float rs[4], rss[4], gmean[4], grstd[4];
  for (int gi = 0; gi < ngroups; gi++) {
    float s = 0.f, ss = 0.f;
    const int nel = cpg << 6;
    for (int e = threadIdx.x; e < nel; e += 256) {
      const float v = red[((gi << cpgShift) + (e >> 6)) * 65 + (e & 63)];
      s += v;
      ss += v * v;
    }
#pragma unroll
    for (int off = 32; off > 0; off >>= 1) {
      s += __shfl_down(s, off);
      ss += __shfl_down(ss, off);
    }
    if (lane == 0) { rs[w] = s; rss[w] = ss; }
    __syncthreads();
    if (threadIdx.x == 0) {
      const float ts = rs[0] + rs[1] + rs[2] + rs[3];
      const float tss = rss[0] + rss[1] + rss[2] + rss[3];
      const float mean = ts / (float)nel;
      const float var = tss / (float)nel - mean * mean;
      gmean[gi] = mean;
      grstd[gi] = rsqrtf(var + 1e-5f);
    }
    __syncthreads();
  }

  if (outF) {
    for (int e = threadIdx.x; e < 4096; e += 256) {
      const int m = e >> 6, n = e & 63;
      const int gi = m >> cpgShift;
      const int c = o0 + m;
      float v = (red[m * 65 + n] - gmean[gi]) * grstd[gi] * gamma[c] + beta[c];
      v = fmaxf(v, 0.f);
      outF[((size_t)b * M + c) * 64 + n] = v;
    }
  }
  if (catOut) {
    for (int e = threadIdx.x; e < 4096; e += 256) {
      const int n = e >> 6, m = e & 63;
      const int gi = m >> cpgShift;
      const int c = o0 + m;
      float v = (red[m * 65 + n] - gmean[gi]) * grstd[gi] * gamma[c] + beta[c];
      v = fmaxf(v, 0.f);
      catOut[((size_t)(b * 64) + n) * catStride + chOff + c] = f2bf(v);
    }
  }
}

// ---------------------------------------------------------------------------
// Anchor gather: G[b][t][c*K+k] = bf16(F[b][c][idx(b,t,k)])
// ---------------------------------------------------------------------------
template <int K, int L, int CC, int Cin>
__global__ __launch_bounds__(256) void gather_kernel(
    const float* __restrict__ F, const int* __restrict__ anc,
    ushort* __restrict__ G) {
  __shared__ float Fl[CC * L];
  __shared__ int sidx[64 * K];
  const int c0 = blockIdx.x * CC;
  const int b = blockIdx.y;
  const int tid = threadIdx.x;
  for (int e = tid; e < 64 * K; e += 256) {
    const int tt = e / K, k = e % K;
    const int a0 = anc[((size_t)b * 64 + tt) * 2 + 0];
    const int a1 = anc[((size_t)b * 64 + tt) * 2 + 1];
    const int left = min(max(a0, 0), L);
    const int right = min(max(a1, 0), L);
    const int seglen = right + 1 - left;
    sidx[e] = min(max(left + (k * seglen) / K, 0), L - 1);
  }
  const float* Fb = F + ((size_t)b * Cin + c0) * L;
  for (int e = tid; e < CC * L; e += 256) Fl[e] = Fb[e];
  __syncthreads();
  constexpr int KK = Cin * K;
  constexpr int PH = (CC * K) / 2;
  for (int f = tid; f < 64 * PH; f += 256) {
    const int t = f / PH;
    const int p = f % PH;
    const int col0 = 2 * p;
    const int cc = col0 / K;
    const int k = col0 % K;
    const float v0 = Fl[cc * L + sidx[t * K + k]];
    const float v1 = Fl[cc * L + sidx[t * K + k + 1]];
    const unsigned pk = (unsigned)f2bf(v0) | ((unsigned)f2bf(v1) << 16);
    *(unsigned*)(G + (size_t)(b * 64 + t) * KK + c0 * K + col0) = pk;
  }
}

// ---------------------------------------------------------------------------
// MFMA GEMM for anchor conv: P[kz][b][n][m] partials (split-K)
// ---------------------------------------------------------------------------
__global__ __launch_bounds__(256) void anchor_mfma_kernel(
    const ushort* __restrict__ G, const ushort* __restrict__ Wb,
    float* __restrict__ P, int KK, int kspan) {
  const int n0 = blockIdx.x * 64;
  const int b = blockIdx.y;
  const int kz = blockIdx.z;
  const int w = threadIdx.x >> 6;
  const int lane = threadIdx.x & 63;
  const int l15 = lane & 15, l4 = lane >> 4;
  const int wk = kspan >> 2;
  const int kbeg = kz * kspan + w * wk;
  const int kend = kbeg + wk;

  f32x4 acc[4][4] = {};
  const ushort* ap[4];
  const ushort* bp[4];
#pragma unroll
  for (int i = 0; i < 4; i++)
    ap[i] = G + ((size_t)b * 64 + i * 16 + l15) * KK + l4 * 8;
#pragma unroll
  for (int j = 0; j < 4; j++)
    bp[j] = Wb + (size_t)(n0 + j * 16 + l15) * KK + l4 * 8;

  for (int k = kbeg; k < kend; k += 32) {
    short8 a[4], bb[4];
#pragma unroll
    for (int i = 0; i < 4; i++) a[i] = *(const short8*)(ap[i] + k);
#pragma unroll
    for (int j = 0; j < 4; j++) bb[j] = *(const short8*)(bp[j] + k);
#pragma unroll
    for (int i = 0; i < 4; i++)
#pragma unroll
      for (int j = 0; j < 4; j++)
        acc[i][j] = __builtin_amdgcn_mfma_f32_16x16x32_bf16(a[i], bb[j],
                                                            acc[i][j], 0, 0, 0);
  }

  __shared__ float red[64 * 65];
  for (int ww = 0; ww < 4; ww++) {
    __syncthreads();
    if (w == ww) {
#pragma unroll
      for (int i = 0; i < 4; i++)
#pragma unroll
        for (int j = 0; j < 4; j++)
#pragma unroll
          for (int r = 0; r < 4; r++) {
            const int m = i * 16 + l4 * 4 + r;
            const int n = j * 16 + l15;
            if (ww == 0)
              red[m * 65 + n] = acc[i][j][r];
            else
              red[m * 65 + n] += acc[i][j][r];
          }
    }
  }
  __syncthreads();
  float* Pp = P + (((size_t)kz * BB + b) * 512 + n0) * 64;
  for (int e = threadIdx.x; e < 4096; e += 256) {
    const int n = e >> 6, m = e & 63;
    Pp[e] = red[m * 65 + n];
  }
}

// ---------------------------------------------------------------------------
// Split-K reduce + valid mask + bias -> bf16 transposed rows (via LDS tile)
// grid (512/64, B)
// ---------------------------------------------------------------------------
__global__ __launch_bounds__(256) void anchor_reduce_kernel(
    const float* __restrict__ P, int ks, const float* __restrict__ bias,
    const int* __restrict__ anc, int L, ushort* __restrict__ Y, int rowStride,
    int chOff) {
  __shared__ float tile[64 * 65];
  __shared__ float sval[64];
  const int o0 = blockIdx.x * 64;
  const int b = blockIdx.y;
  if (threadIdx.x < 64) {
    const int t = threadIdx.x;
    const int a0 = anc[((size_t)b * 64 + t) * 2 + 0];
    const int a1 = anc[((size_t)b * 64 + t) * 2 + 1];
    const int left = min(max(a0, 0), L);
    const int right = min(max(a1, 0), L);
    sval[t] = (right > left) ? 1.f : 0.f;
  }
  __syncthreads();
  for (int e = threadIdx.x; e < 4096; e += 256) {
    const int nl = e >> 6, m = e & 63;
    const int n = o0 + nl;
    float s = 0.f;
    for (int z = 0; z < ks; z++)
      s += P[(((size_t)z * BB + b) * 512 + n) * 64 + m];
    tile[nl * 65 + m] = s * sval[m] + bias[n];
  }
  __syncthreads();
  for (int e = threadIdx.x; e < 4096; e += 256) {
    const int m = e >> 6, nl = e & 63;
    Y[((size_t)(b * 64) + m) * rowStride + chOff + o0 + nl] =
        f2bf(tile[nl * 65 + m]);
  }
}

extern "C" void kernel_launch(void* const* d_in, const int* in_sizes, int n_in,
                              void* d_out, int out_size, void* d_ws,
                              size_t ws_size, hipStream_t stream) {
  const float* feature      = (const float*)d_in[0];
  const float* frame_feat   = (const float*)d_in[1];
  const int*   segments     = (const int*)d_in[2];
  const int*   frame_segs   = (const int*)d_in[3];
  const float* feat_lastcls = (const float*)d_in[4];
  const int*   anchor       = (const int*)d_in[5];
  const int*   frame_anchor = (const int*)d_in[6];
  const float* locres       = (const float*)d_in[8];
  const float* w_cur  = (const float*)d_in[9];
  const float* b_cur  = (const float*)d_in[10];
  const float* g_cur  = (const float*)d_in[11];
  const float* be_cur = (const float*)d_in[12];
  const float* w_lr   = (const float*)d_in[13];
  const float* b_lr   = (const float*)d_in[14];
  const float* g_lr   = (const float*)d_in[15];
  const float* be_lr  = (const float*)d_in[16];
  const float* w_roi  = (const float*)d_in[17];
  const float* b_roi  = (const float*)d_in[18];
  const float* g_roi  = (const float*)d_in[19];
  const float* be_roi = (const float*)d_in[20];
  const float* w_cp   = (const float*)d_in[21];  // [512,1024,16]
  const float* b_cp   = (const float*)d_in[22];
  const float* w_cp0  = (const float*)d_in[23];  // [512,512,8]
  const float* b_cp0  = (const float*)d_in[24];
  const float* w_prop = (const float*)d_in[25];  // [512,3572]
  const float* b_prop = (const float*)d_in[26];
  const float* g_prop = (const float*)d_in[27];
  const float* be_prop= (const float*)d_in[28];

  float* out_main = (float*)d_out;                  // [8,512,64]
  float* feat_lr  = (float*)d_out + BB * 512 * 64;  // [8,1024,64]

  // workspace layout (ushort elements first, then f32 partials)
  ushort* cat_t = (ushort*)d_ws;            // 1,835,008
  ushort* Ft    = cat_t + 1835008;          // 262,144
  ushort* XbmpT = Ft + 262144;              // 262,144
  ushort* FconT = XbmpT + 262144;           // 262,144
  ushort* Wcur  = FconT + 262144;           // 262,144
  ushort* Wlr   = Wcur + 262144;            // 524,288
  ushort* Wroi  = Wlr + 524288;             // 262,144
  ushort* Wprop = Wroi + 262144;            // 1,835,008
  ushort* Wcp   = Wprop + 1835008;          // 8,388,608
  ushort* Wcp0  = Wcp + 8388608;            // 2,097,152
  ushort* G1    = Wcp0 + 2097152;           // 8,388,608
  ushort* G0    = G1 + 8388608;             // 2,097,152
  ushort* FlrT  = G0 + 2097152;             // 524,288  [8*64][1024]
  ushort* FfT   = FlrT + 524288;            // 1,048,576 [8*256][512]
  float*  P1    = (float*)(FfT + 1048576);  // 1,048,576 f
  float*  P0    = P1 + 1048576;             // 524,288 f
  // total ~62.4 MB

  // --- weight conversions ---
  cvt_bf16_kernel<<<8192, 256, 0, stream>>>((const float4*)w_cp, (uint2*)Wcp, 2097152);
  cvt_bf16_kernel<<<2048, 256, 0, stream>>>((const float4*)w_cp0, (uint2*)Wcp0, 524288);
  cvt_bf16_kernel<<<256, 256, 0, stream>>>((const float4*)w_cur, (uint2*)Wcur, 65536);
  cvt_bf16_kernel<<<512, 256, 0, stream>>>((const float4*)w_lr, (uint2*)Wlr, 131072);
  cvt_bf16_kernel<<<256, 256, 0, stream>>>((const float4*)w_roi, (uint2*)Wroi, 65536);
  cvt_pad_wprop_kernel<<<3584, 256, 0, stream>>>(w_prop, (unsigned*)Wprop);

  // --- activation transposes ---
  transpose_cvt_kernel<<<dim3(8, 1, BB), 256, 0, stream>>>(feature, Ft, 512, 64, 512, 0);
  transpose_cvt_kernel<<<dim3(8, 4, BB), 256, 0, stream>>>(frame_feat, FfT, 512, 256, 512, 0);

  // 1. fm_short -> cat[1536:2048]
  gemm_gn_relu_kernel<<<dim3(8, BB), 256, 0, stream>>>(
      Ft, Wcur, b_cur, g_cur, be_cur, 512, 512, 4, nullptr, cat_t, CATP, 1536);

  // 2. feat_lr (output #2, f32) + transposed bf16 copy FlrT
  gemm_gn_relu_kernel<<<dim3(16, BB), 256, 0, stream>>>(
      Ft, Wlr, b_lr, g_lr, be_lr, 512, 1024, 5, feat_lr, FlrT, 1024, 0);

  // 3. prop_feature -> cat[512:1536]
  bmp_t_kernel<1024, 64><<<dim3(64, BB), 256, 0, stream>>>(
      FlrT, segments, cat_t, CATP, 512);

  // 4. prop_roi: bmp(FfT) -> XbmpT; GEMM+GN -> cat[0:512]
  bmp_t_kernel<512, 256><<<dim3(64, BB), 256, 0, stream>>>(
      FfT, frame_segs, XbmpT, 512, 0);
  gemm_gn_relu_kernel<<<dim3(8, BB), 256, 0, stream>>>(
      XbmpT, Wroi, b_roi, g_roi, be_roi, 512, 512, 4, nullptr, cat_t, CATP, 0);

  // 5. con_feature -> cat[2546:3058]
  gather_kernel<16, 64, 64, 1024><<<dim3(16, BB), 256, 0, stream>>>(feat_lr, anchor, G1);
  anchor_mfma_kernel<<<dim3(8, BB, 4), 256, 0, stream>>>(G1, Wcp, P1, 16384, 4096);
  anchor_reduce_kernel<<<dim3(8, BB), 256, 0, stream>>>(P1, 4, b_cp, anchor, 64, cat_t, CATP, 2546);

  // 6. frame_con -> FconT; prop_con -> cat[3058:3570]
  gather_kernel<8, 256, 16, 512><<<dim3(32, BB), 256, 0, stream>>>(frame_feat, frame_anchor, G0);
  anchor_mfma_kernel<<<dim3(8, BB, 2), 256, 0, stream>>>(G0, Wcp0, P0, 4096, 2048);
  anchor_reduce_kernel<<<dim3(8, BB), 256, 0, stream>>>(P0, 2, b_cp0, frame_anchor, 256, FconT, 512, 0);
  gemm_gn_relu_kernel<<<dim3(8, BB), 256, 0, stream>>>(
      FconT, Wroi, b_roi, g_roi, be_roi, 512, 512, 4, nullptr, cat_t, CATP, 3058);

  // 7. feature_lastclass -> cat[2048:2546]; LocResult+pad -> cat[3570:3584]
  transpose_cvt_kernel<<<dim3(8, 1, BB), 256, 0, stream>>>(feat_lastcls, cat_t, 498, 64, CATP, 2048);
  locres_pad_kernel<<<28, 256, 0, stream>>>(locres, cat_t);

  // 8. final projection -> out_main (f32)
  gemm_gn_relu_kernel<<<dim3(8, BB), 256, 0, stream>>>(
      cat_t, Wprop, b_prop, g_prop, be_prop, CATP, 512, 4, out_main, nullptr, CATP, 0);
}

// Round 5
// 419.605 us; speedup vs baseline: 1.1030x; 1.1030x over previous
//
#include <hip/hip_runtime.h>
#include <math.h>

#define BB 8
#define CATP 3584   // padded cat K (3572 -> 3584, zeros)
#define CAT_REAL 3572

typedef __attribute__((ext_vector_type(8))) short short8;
typedef __attribute__((ext_vector_type(4))) float f32x4;

__device__ inline ushort f2bf(float f) {
  union { float f; unsigned u; } x;
  x.f = f;
  return (ushort)((x.u + 0x7FFFu + ((x.u >> 16) & 1u)) >> 16);
}
__device__ inline float bf2f(unsigned us) {
  union { unsigned u; float f; } x;
  x.u = us << 16;
  return x.f;
}

// ---------------------------------------------------------------------------
// Batched f32 -> bf16 convert for 5 weight tensors in one launch.
// ---------------------------------------------------------------------------
__global__ __launch_bounds__(256) void cvt_multi_kernel(
    const float4* __restrict__ S0, uint2* __restrict__ D0, int n0,
    const float4* __restrict__ S1, uint2* __restrict__ D1, int n1,
    const float4* __restrict__ S2, uint2* __restrict__ D2, int n2,
    const float4* __restrict__ S3, uint2* __restrict__ D3, int n3,
    const float4* __restrict__ S4, uint2* __restrict__ D4, int n4t) {
  int i = blockIdx.x * 256 + threadIdx.x;
  const float4* S;
  uint2* D;
  if (i < n0) { S = S0; D = D0; }
  else {
    i -= n0;
    if (i < n1) { S = S1; D = D1; }
    else {
      i -= n1;
      if (i < n2) { S = S2; D = D2; }
      else {
        i -= n2;
        if (i < n3) { S = S3; D = D3; }
        else {
          i -= n3;
          if (i >= n4t) return;
          S = S4; D = D4;
        }
      }
    }
  }
  const float4 v = S[i];
  uint2 o;
  o.x = (unsigned)f2bf(v.x) | ((unsigned)f2bf(v.y) << 16);
  o.y = (unsigned)f2bf(v.z) | ((unsigned)f2bf(v.w) << 16);
  D[i] = o;
}

// w_prop [512][3572] f32 -> [512][3584] bf16 with zero pad
__global__ __launch_bounds__(256) void cvt_pad_wprop_kernel(
    const float* __restrict__ W, unsigned* __restrict__ Y) {
  const int idx = blockIdx.x * 256 + threadIdx.x;
  if (idx >= 512 * (CATP / 2)) return;
  const int p = idx % (CATP / 2);
  const int o = idx / (CATP / 2);
  const int c0 = p * 2;
  unsigned pk = 0;
  if (c0 < CAT_REAL) {
    const float* w = W + (size_t)o * CAT_REAL + c0;
    pk = (unsigned)f2bf(w[0]) | ((unsigned)f2bf(w[1]) << 16);
  }
  Y[(size_t)o * (CATP / 2) + p] = pk;
}

// ---------------------------------------------------------------------------
// Transpose+convert: X f32 [B][C][L] -> Y bf16 rows (b*L+l)*rowStride+chOff+c
// grid (ceil(C/64), L/64, B)
// ---------------------------------------------------------------------------
__global__ __launch_bounds__(256) void transpose_cvt_kernel(
    const float* __restrict__ X, ushort* __restrict__ Y, int C, int L,
    int rowStride, int chOff) {
  __shared__ float tile[64 * 65];
  const int c0 = blockIdx.x * 64;
  const int l0 = blockIdx.y * 64;
  const int b = blockIdx.z;
  for (int e = threadIdx.x; e < 4096; e += 256) {
    const int cc = e >> 6, ll = e & 63;
    const int c = c0 + cc;
    tile[cc * 65 + ll] = (c < C) ? X[((size_t)b * C + c) * L + l0 + ll] : 0.f;
  }
  __syncthreads();
  for (int e = threadIdx.x; e < 4096; e += 256) {
    const int ll = e >> 6, cc = e & 63;
    const int c = c0 + cc;
    if (c < C)
      Y[((size_t)b * L + l0 + ll) * rowStride + chOff + c] =
          f2bf(tile[cc * 65 + ll]);
  }
}

// LocResult [8][2][64] -> cat[3570:3572], plus zero-pad cat[3572:3584]
__global__ __launch_bounds__(256) void locres_pad_kernel(
    const float* __restrict__ L, ushort* __restrict__ cat) {
  const int idx = blockIdx.x * 256 + threadIdx.x;
  if (idx >= BB * 64 * 14) return;
  const int j = idx % 14;
  const int t = (idx / 14) % 64;
  const int b = idx / (14 * 64);
  const ushort v = (j < 2) ? f2bf(L[((size_t)b * 2 + j) * 64 + t]) : (ushort)0;
  cat[((size_t)(b * 64) + t) * CATP + 3570 + j] = v;
}

// ---------------------------------------------------------------------------
// BoundaryMaxPooling on transposed bf16 input Xt [(b*L+l)*C + c].
// Block = (t, b). The l-range is split across the 4 waves (stride 4, 2x
// unrolled => ~8 independent loads in flight per lane); each wave covers all
// channel pairs in 64-lane chunks. Partials in LDS [wave][pair] (conflict
// free), 4-way reduce, packed coalesced store. grid (64, B).
// ---------------------------------------------------------------------------
template <int C, int L>
__global__ __launch_bounds__(256) void bmp_t_kernel(
    const ushort* __restrict__ Xt, const int* __restrict__ segs,
    ushort* __restrict__ Y, int rowStride, int chOff) {
  constexpr int C2 = C / 2;   // channels per half
  constexpr int P2 = C2 / 2;  // pairs per half
  constexpr int CH = P2 / 64; // 64-pair chunks per half
  const int t = blockIdx.x;
  const int b = blockIdx.y;
  const int w = threadIdx.x >> 6;
  const int lane = threadIdx.x & 63;
  const int* sg = segs + ((size_t)b * 64 + t) * 4;
  __shared__ float2 pmax[4][2 * P2];
  const ushort* Xb = Xt + (size_t)b * L * C;
#pragma unroll
  for (int h = 0; h < 2; h++) {
    const int s = min(max(sg[2 * h], 0), L - 1);
    const int e = max(min(max(sg[2 * h + 1], 0), L - 1), s);
#pragma unroll
    for (int q = 0; q < CH; q++) {
      const int p = q * 64 + lane;
      const ushort* base = Xb + h * C2 + 2 * p;
      float a0 = -INFINITY, a1 = -INFINITY;
      float c0 = -INFINITY, c1 = -INFINITY;
      int l = s + w;
      for (; l + 4 <= e; l += 8) {
        const unsigned u0 = *(const unsigned*)(base + (size_t)l * C);
        const unsigned u1 = *(const unsigned*)(base + (size_t)(l + 4) * C);
        a0 = fmaxf(a0, bf2f(u0 & 0xffffu));
        a1 = fmaxf(a1, bf2f(u0 >> 16));
        c0 = fmaxf(c0, bf2f(u1 & 0xffffu));
        c1 = fmaxf(c1, bf2f(u1 >> 16));
      }
      if (l <= e) {
        const unsigned u0 = *(const unsigned*)(base + (size_t)l * C);
        a0 = fmaxf(a0, bf2f(u0 & 0xffffu));
        a1 = fmaxf(a1, bf2f(u0 >> 16));
      }
      pmax[w][h * P2 + p] = make_float2(fmaxf(a0, c0), fmaxf(a1, c1));
    }
  }
  __syncthreads();
  for (int idx = threadIdx.x; idx < 2 * P2; idx += 256) {
    float2 m = pmax[0][idx];
#pragma unroll
    for (int ww = 1; ww < 4; ww++) {
      const float2 v = pmax[ww][idx];
      m.x = fmaxf(m.x, v.x);
      m.y = fmaxf(m.y, v.y);
    }
    const unsigned o = (unsigned)f2bf(m.x) | ((unsigned)f2bf(m.y) << 16);
    *(unsigned*)(Y + ((size_t)(b * 64) + t) * rowStride + chOff + 2 * idx) = o;
  }
}

// ---------------------------------------------------------------------------
// Fused bf16 MFMA GEMM + GroupNorm + ReLU.
// Block: (64 o) x (64 t, one b); 4 waves split K; LDS reduce; in-block GN.
// Writes f32 [b][M][64] (outF) and/or bf16 transposed rows (catOut).
// grid (M/64, B).
// ---------------------------------------------------------------------------
__global__ __launch_bounds__(256) void gemm_gn_relu_kernel(
    const ushort* __restrict__ Xt, const ushort* __restrict__ Wb,
    const float* __restrict__ bias, const float* __restrict__ gamma,
    const float* __restrict__ beta, int Kp, int M, int cpgShift,
    float* __restrict__ outF, ushort* __restrict__ catOut, int catStride,
    int chOff) {
  const int o0 = blockIdx.x * 64;
  const int b = blockIdx.y;
  const int w = threadIdx.x >> 6;
  const int lane = threadIdx.x & 63;
  const int l15 = lane & 15, l4 = lane >> 4;
  const int wk = Kp >> 2;
  const int kbeg = w * wk, kend = kbeg + wk;

  f32x4 acc[4][4] = {};
  const ushort* ap[4];
  const ushort* bp[4];
#pragma unroll
  for (int i = 0; i < 4; i++)
    ap[i] = Wb + (size_t)(o0 + i * 16 + l15) * Kp + l4 * 8;
#pragma unroll
  for (int j = 0; j < 4; j++)
    bp[j] = Xt + (size_t)(b * 64 + j * 16 + l15) * Kp + l4 * 8;

  for (int k = kbeg; k < kend; k += 32) {
    short8 a[4], x[4];
#pragma unroll
    for (int i = 0; i < 4; i++) a[i] = *(const short8*)(ap[i] + k);
#pragma unroll
    for (int j = 0; j < 4; j++) x[j] = *(const short8*)(bp[j] + k);
#pragma unroll
    for (int i = 0; i < 4; i++)
#pragma unroll
      for (int j = 0; j < 4; j++)
        acc[i][j] = __builtin_amdgcn_mfma_f32_16x16x32_bf16(a[i], x[j],
                                                            acc[i][j], 0, 0, 0);
  }

  __shared__ float red[64 * 65];
  for (int ww = 0; ww < 4; ww++) {
    __syncthreads();
    if (w == ww) {
#pragma unroll
      for (int i = 0; i < 4; i++)
#pragma unroll
        for (int j = 0; j < 4; j++)
#pragma unroll
          for (int r = 0; r < 4; r++) {
            const int m = i * 16 + l4 * 4 + r;
            const int n = j * 16 + l15;
            if (ww == 0)
              red[m * 65 + n] = acc[i][j][r] + bias[o0 + m];
            else
              red[m * 65 + n] += acc[i][j][r];
          }
    }
  }
  __syncthreads();

  const int cpg = 1 << cpgShift;
  const int ngroups = 64 >> cpgShift;
  __shared__ float rs[4], rss[4], gmean[4], grstd[4];
  for (int gi = 0; gi < ngroups; gi++) {
    float s = 0.f, ss = 0.f;
    const int nel = cpg << 6;
    for (int e = threadIdx.x; e < nel; e += 256) {
      const float v = red[((gi << cpgShift) + (e >> 6)) * 65 + (e & 63)];
      s += v;
      ss += v * v;
    }
#pragma unroll
    for (int off = 32; off > 0; off >>= 1) {
      s += __shfl_down(s, off);
      ss += __shfl_down(ss, off);
    }
    if (lane == 0) { rs[w] = s; rss[w] = ss; }
    __syncthreads();
    if (threadIdx.x == 0) {
      const float ts = rs[0] + rs[1] + rs[2] + rs[3];
      const float tss = rss[0] + rss[1] + rss[2] + rss[3];
      const float mean = ts / (float)nel;
      const float var = tss / (float)nel - mean * mean;
      gmean[gi] = mean;
      grstd[gi] = rsqrtf(var + 1e-5f);
    }
    __syncthreads();
  }

  if (outF) {
    for (int e = threadIdx.x; e < 4096; e += 256) {
      const int m = e >> 6, n = e & 63;
      const int gi = m >> cpgShift;
      const int c = o0 + m;
      float v = (red[m * 65 + n] - gmean[gi]) * grstd[gi] * gamma[c] + beta[c];
      v = fmaxf(v, 0.f);
      outF[((size_t)b * M + c) * 64 + n] = v;
    }
  }
  if (catOut) {
    for (int e = threadIdx.x; e < 4096; e += 256) {
      const int n = e >> 6, m = e & 63;
      const int gi = m >> cpgShift;
      const int c = o0 + m;
      float v = (red[m * 65 + n] - gmean[gi]) * grstd[gi] * gamma[c] + beta[c];
      v = fmaxf(v, 0.f);
      catOut[((size_t)(b * 64) + n) * catStride + chOff + c] = f2bf(v);
    }
  }
}

// ---------------------------------------------------------------------------
// Anchor gather: G[b][t][c*K+k] = bf16(F[b][c][idx(b,t,k)])
// ---------------------------------------------------------------------------
template <int K, int L, int CC, int Cin>
__global__ __launch_bounds__(256) void gather_kernel(
    const float* __restrict__ F, const int* __restrict__ anc,
    ushort* __restrict__ G) {
  __shared__ float Fl[CC * L];
  __shared__ int sidx[64 * K];
  const int c0 = blockIdx.x * CC;
  const int b = blockIdx.y;
  const int tid = threadIdx.x;
  for (int e = tid; e < 64 * K; e += 256) {
    const int tt = e / K, k = e % K;
    const int a0 = anc[((size_t)b * 64 + tt) * 2 + 0];
    const int a1 = anc[((size_t)b * 64 + tt) * 2 + 1];
    const int left = min(max(a0, 0), L);
    const int right = min(max(a1, 0), L);
    const int seglen = right + 1 - left;
    sidx[e] = min(max(left + (k * seglen) / K, 0), L - 1);
  }
  const float* Fb = F + ((size_t)b * Cin + c0) * L;
  for (int e = tid; e < CC * L; e += 256) Fl[e] = Fb[e];
  __syncthreads();
  constexpr int KK = Cin * K;
  constexpr int PH = (CC * K) / 2;
  for (int f = tid; f < 64 * PH; f += 256) {
    const int t = f / PH;
    const int p = f % PH;
    const int col0 = 2 * p;
    const int cc = col0 / K;
    const int k = col0 % K;
    const float v0 = Fl[cc * L + sidx[t * K + k]];
    const float v1 = Fl[cc * L + sidx[t * K + k + 1]];
    const unsigned pk = (unsigned)f2bf(v0) | ((unsigned)f2bf(v1) << 16);
    *(unsigned*)(G + (size_t)(b * 64 + t) * KK + c0 * K + col0) = pk;
  }
}

// ---------------------------------------------------------------------------
// MFMA GEMM for anchor conv: P[kz][b][n][m] partials (split-K)
// ---------------------------------------------------------------------------
__global__ __launch_bounds__(256) void anchor_mfma_kernel(
    const ushort* __restrict__ G, const ushort* __restrict__ Wb,
    float* __restrict__ P, int KK, int kspan) {
  const int n0 = blockIdx.x * 64;
  const int b = blockIdx.y;
  const int kz = blockIdx.z;
  const int w = threadIdx.x >> 6;
  const int lane = threadIdx.x & 63;
  const int l15 = lane & 15, l4 = lane >> 4;
  const int wk = kspan >> 2;
  const int kbeg = kz * kspan + w * wk;
  const int kend = kbeg + wk;

  f32x4 acc[4][4] = {};
  const ushort* ap[4];
  const ushort* bp[4];
#pragma unroll
  for (int i = 0; i < 4; i++)
    ap[i] = G + ((size_t)b * 64 + i * 16 + l15) * KK + l4 * 8;
#pragma unroll
  for (int j = 0; j < 4; j++)
    bp[j] = Wb + (size_t)(n0 + j * 16 + l15) * KK + l4 * 8;

  for (int k = kbeg; k < kend; k += 32) {
    short8 a[4], bb[4];
#pragma unroll
    for (int i = 0; i < 4; i++) a[i] = *(const short8*)(ap[i] + k);
#pragma unroll
    for (int j = 0; j < 4; j++) bb[j] = *(const short8*)(bp[j] + k);
#pragma unroll
    for (int i = 0; i < 4; i++)
#pragma unroll
      for (int j = 0; j < 4; j++)
        acc[i][j] = __builtin_amdgcn_mfma_f32_16x16x32_bf16(a[i], bb[j],
                                                            acc[i][j], 0, 0, 0);
  }

  __shared__ float red[64 * 65];
  for (int ww = 0; ww < 4; ww++) {
    __syncthreads();
    if (w == ww) {
#pragma unroll
      for (int i = 0; i < 4; i++)
#pragma unroll
        for (int j = 0; j < 4; j++)
#pragma unroll
          for (int r = 0; r < 4; r++) {
            const int m = i * 16 + l4 * 4 + r;
            const int n = j * 16 + l15;
            if (ww == 0)
              red[m * 65 + n] = acc[i][j][r];
            else
              red[m * 65 + n] += acc[i][j][r];
          }
    }
  }
  __syncthreads();
  float* Pp = P + (((size_t)kz * BB + b) * 512 + n0) * 64;
  for (int e = threadIdx.x; e < 4096; e += 256) {
    const int n = e >> 6, m = e & 63;
    Pp[e] = red[m * 65 + n];
  }
}

// ---------------------------------------------------------------------------
// Split-K reduce + valid mask + bias -> bf16 transposed rows (via LDS tile)
// grid (512/64, B)
// ---------------------------------------------------------------------------
__global__ __launch_bounds__(256) void anchor_reduce_kernel(
    const float* __restrict__ P, int ks, const float* __restrict__ bias,
    const int* __restrict__ anc, int L, ushort* __restrict__ Y, int rowStride,
    int chOff) {
  __shared__ float tile[64 * 65];
  __shared__ float sval[64];
  const int o0 = blockIdx.x * 64;
  const int b = blockIdx.y;
  if (threadIdx.x < 64) {
    const int t = threadIdx.x;
    const int a0 = anc[((size_t)b * 64 + t) * 2 + 0];
    const int a1 = anc[((size_t)b * 64 + t) * 2 + 1];
    const int left = min(max(a0, 0), L);
    const int right = min(max(a1, 0), L);
    sval[t] = (right > left) ? 1.f : 0.f;
  }
  __syncthreads();
  for (int e = threadIdx.x; e < 4096; e += 256) {
    const int nl = e >> 6, m = e & 63;
    const int n = o0 + nl;
    float s = 0.f;
    for (int z = 0; z < ks; z++)
      s += P[(((size_t)z * BB + b) * 512 + n) * 64 + m];
    tile[nl * 65 + m] = s * sval[m] + bias[n];
  }
  __syncthreads();
  for (int e = threadIdx.x; e < 4096; e += 256) {
    const int m = e >> 6, nl = e & 63;
    Y[((size_t)(b * 64) + m) * rowStride + chOff + o0 + nl] =
        f2bf(tile[nl * 65 + m]);
  }
}

extern "C" void kernel_launch(void* const* d_in, const int* in_sizes, int n_in,
                              void* d_out, int out_size, void* d_ws,
                              size_t ws_size, hipStream_t stream) {
  const float* feature      = (const float*)d_in[0];
  const float* frame_feat   = (const float*)d_in[1];
  const int*   segments     = (const int*)d_in[2];
  const int*   frame_segs   = (const int*)d_in[3];
  const float* feat_lastcls = (const float*)d_in[4];
  const int*   anchor       = (const int*)d_in[5];
  const int*   frame_anchor = (const int*)d_in[6];
  const float* locres       = (const float*)d_in[8];
  const float* w_cur  = (const float*)d_in[9];
  const float* b_cur  = (const float*)d_in[10];
  const float* g_cur  = (const float*)d_in[11];
  const float* be_cur = (const float*)d_in[12];
  const float* w_lr   = (const float*)d_in[13];
  const float* b_lr   = (const float*)d_in[14];
  const float* g_lr   = (const float*)d_in[15];
  const float* be_lr  = (const float*)d_in[16];
  const float* w_roi  = (const float*)d_in[17];
  const float* b_roi  = (const float*)d_in[18];
  const float* g_roi  = (const float*)d_in[19];
  const float* be_roi = (const float*)d_in[20];
  const float* w_cp   = (const float*)d_in[21];  // [512,1024,16]
  const float* b_cp   = (const float*)d_in[22];
  const float* w_cp0  = (const float*)d_in[23];  // [512,512,8]
  const float* b_cp0  = (const float*)d_in[24];
  const float* w_prop = (const float*)d_in[25];  // [512,3572]
  const float* b_prop = (const float*)d_in[26];
  const float* g_prop = (const float*)d_in[27];
  const float* be_prop= (const float*)d_in[28];

  float* out_main = (float*)d_out;                  // [8,512,64]
  float* feat_lr  = (float*)d_out + BB * 512 * 64;  // [8,1024,64]

  // workspace layout (ushort elements first, then f32 partials)
  ushort* cat_t = (ushort*)d_ws;            // 1,835,008
  ushort* Ft    = cat_t + 1835008;          // 262,144
  ushort* XbmpT = Ft + 262144;              // 262,144
  ushort* FconT = XbmpT + 262144;           // 262,144
  ushort* Wcur  = FconT + 262144;           // 262,144
  ushort* Wlr   = Wcur + 262144;            // 524,288
  ushort* Wroi  = Wlr + 524288;             // 262,144
  ushort* Wprop = Wroi + 262144;            // 1,835,008
  ushort* Wcp   = Wprop + 1835008;          // 8,388,608
  ushort* Wcp0  = Wcp + 8388608;            // 2,097,152
  ushort* G1    = Wcp0 + 2097152;           // 8,388,608
  ushort* G0    = G1 + 8388608;             // 2,097,152
  ushort* FlrT  = G0 + 2097152;             // 524,288  [8*64][1024]
  ushort* FfT   = FlrT + 524288;            // 1,048,576 [8*256][512]
  float*  P1    = (float*)(FfT + 1048576);  // 1,048,576 f
  float*  P0    = P1 + 1048576;             // 524,288 f
  // total ~62.4 MB

  // --- weight conversions (one batched launch + padded w_prop) ---
  cvt_multi_kernel<<<11264, 256, 0, stream>>>(
      (const float4*)w_cp,  (uint2*)Wcp,  2097152,
      (const float4*)w_cp0, (uint2*)Wcp0, 524288,
      (const float4*)w_cur, (uint2*)Wcur, 65536,
      (const float4*)w_lr,  (uint2*)Wlr,  131072,
      (const float4*)w_roi, (uint2*)Wroi, 65536);
  cvt_pad_wprop_kernel<<<3584, 256, 0, stream>>>(w_prop, (unsigned*)Wprop);

  // --- activation transposes ---
  transpose_cvt_kernel<<<dim3(8, 1, BB), 256, 0, stream>>>(feature, Ft, 512, 64, 512, 0);
  transpose_cvt_kernel<<<dim3(8, 4, BB), 256, 0, stream>>>(frame_feat, FfT, 512, 256, 512, 0);

  // 1. fm_short -> cat[1536:2048]
  gemm_gn_relu_kernel<<<dim3(8, BB), 256, 0, stream>>>(
      Ft, Wcur, b_cur, g_cur, be_cur, 512, 512, 4, nullptr, cat_t, CATP, 1536);

  // 2. feat_lr (output #2, f32) + transposed bf16 copy FlrT
  gemm_gn_relu_kernel<<<dim3(16, BB), 256, 0, stream>>>(
      Ft, Wlr, b_lr, g_lr, be_lr, 512, 1024, 5, feat_lr, FlrT, 1024, 0);

  // 3. prop_feature -> cat[512:1536]
  bmp_t_kernel<1024, 64><<<dim3(64, BB), 256, 0, stream>>>(
      FlrT, segments, cat_t, CATP, 512);

  // 4. prop_roi: bmp(FfT) -> XbmpT; GEMM+GN -> cat[0:512]
  bmp_t_kernel<512, 256><<<dim3(64, BB), 256, 0, stream>>>(
      FfT, frame_segs, XbmpT, 512, 0);
  gemm_gn_relu_kernel<<<dim3(8, BB), 256, 0, stream>>>(
      XbmpT, Wroi, b_roi, g_roi, be_roi, 512, 512, 4, nullptr, cat_t, CATP, 0);

  // 5. con_feature -> cat[2546:3058]
  gather_kernel<16, 64, 64, 1024><<<dim3(16, BB), 256, 0, stream>>>(feat_lr, anchor, G1);
  anchor_mfma_kernel<<<dim3(8, BB, 4), 256, 0, stream>>>(G1, Wcp, P1, 16384, 4096);
  anchor_reduce_kernel<<<dim3(8, BB), 256, 0, stream>>>(P1, 4, b_cp, anchor, 64, cat_t, CATP, 2546);

  // 6. frame_con -> FconT; prop_con -> cat[3058:3570]
  gather_kernel<8, 256, 16, 512><<<dim3(32, BB), 256, 0, stream>>>(frame_feat, frame_anchor, G0);
  anchor_mfma_kernel<<<dim3(8, BB, 2), 256, 0, stream>>>(G0, Wcp0, P0, 4096, 2048);
  anchor_reduce_kernel<<<dim3(8, BB), 256, 0, stream>>>(P0, 2, b_cp0, frame_anchor, 256, FconT, 512, 0);
  gemm_gn_relu_kernel<<<dim3(8, BB), 256, 0, stream>>>(
      FconT, Wroi, b_roi, g_roi, be_roi, 512, 512, 4, nullptr, cat_t, CATP, 3058);

  // 7. feature_lastclass -> cat[2048:2546]; LocResult+pad -> cat[3570:3584]
  transpose_cvt_kernel<<<dim3(8, 1, BB), 256, 0, stream>>>(feat_lastcls, cat_t, 498, 64, CATP, 2048);
  locres_pad_kernel<<<28, 256, 0, stream>>>(locres, cat_t);

  // 8. final projection -> out_main (f32)
  gemm_gn_relu_kernel<<<dim3(8, BB), 256, 0, stream>>>(
      cat_t, Wprop, b_prop, g_prop, be_prop, CATP, 512, 4, out_main, nullptr, CATP, 0);
}

// Round 6
// 311.984 us; speedup vs baseline: 1.4835x; 1.3450x over previous
//
#include <hip/hip_runtime.h>
#include <math.h>

#define BB 8
#define CATP 3584   // padded cat K (3572 -> 3584, zeros)
#define CAT_REAL 3572

typedef __attribute__((ext_vector_type(8))) short short8;
typedef __attribute__((ext_vector_type(4))) float f32x4;

__device__ inline ushort f2bf(float f) {
  union { float f; unsigned u; } x;
  x.f = f;
  return (ushort)((x.u + 0x7FFFu + ((x.u >> 16) & 1u)) >> 16);
}
__device__ inline float bf2f(unsigned us) {
  union { unsigned u; float f; } x;
  x.u = us << 16;
  return x.f;
}

// ---------------------------------------------------------------------------
// L1: all flat weight converts + padded w_prop in ONE launch.
// i in [0,262144): flat float4 converts (w_cur | w_lr -> Wcomb, w_roi).
// i in [262144, 262144+917504): w_prop [512][3572] -> [512][3584] bf16 pad.
// ---------------------------------------------------------------------------
__global__ __launch_bounds__(256) void cvt_weights_kernel(
    const float4* __restrict__ w_cur, const float4* __restrict__ w_lr,
    const float4* __restrict__ w_roi, uint2* __restrict__ Wcomb4,
    uint2* __restrict__ Wroi4, const float* __restrict__ w_prop,
    unsigned* __restrict__ Wprop) {
  int i = blockIdx.x * 256 + threadIdx.x;
  if (i < 262144) {
    const float4* S;
    uint2* D;
    if (i < 196608) {  // Wcomb = [w_cur(512x512); w_lr(1024x512)]
      S = (i < 65536) ? (w_cur + i) : (w_lr + (i - 65536));
      D = Wcomb4 + i;
    } else {
      S = w_roi + (i - 196608);
      D = Wroi4 + (i - 196608);
    }
    const float4 v = *S;
    uint2 o;
    o.x = (unsigned)f2bf(v.x) | ((unsigned)f2bf(v.y) << 16);
    o.y = (unsigned)f2bf(v.z) | ((unsigned)f2bf(v.w) << 16);
    *D = o;
    return;
  }
  const int j = i - 262144;  // [0, 512*1792)
  if (j >= 512 * 1792) return;
  const int p = j % 1792;
  const int o = j / 1792;
  const int c0 = 2 * p;
  unsigned pk = 0;
  if (c0 < CAT_REAL) {
    const float* w = w_prop + (size_t)o * CAT_REAL + c0;
    pk = (unsigned)f2bf(w[0]) | ((unsigned)f2bf(w[1]) << 16);
  }
  Wprop[(size_t)o * 1792 + p] = pk;
}

// ---------------------------------------------------------------------------
// L2: conv-weight transpose-convert: W [O][C][K] f32 -> [O][K][C] bf16.
// One block per o; LDS-staged chunks, padded stride. bid<512: w_cp, else w_cp0.
// ---------------------------------------------------------------------------
template <int C, int K>
__device__ void cpT_body(const float* __restrict__ W, ushort* __restrict__ D,
                         int o, float* tile /* 256*(K+1) floats */) {
  for (int c0 = 0; c0 < C; c0 += 256) {
    __syncthreads();
    for (int e = threadIdx.x; e < 256 * K; e += 256) {
      const int c = e / K, k = e % K;
      tile[c * (K + 1) + k] = W[(size_t)o * C * K + (size_t)c0 * K + e];
    }
    __syncthreads();
    for (int e = threadIdx.x; e < K * 128; e += 256) {
      const int k = e / 128, cp = e % 128;
      const float v0 = tile[(2 * cp) * (K + 1) + k];
      const float v1 = tile[(2 * cp + 1) * (K + 1) + k];
      const unsigned pk = (unsigned)f2bf(v0) | ((unsigned)f2bf(v1) << 16);
      *(unsigned*)(D + ((size_t)o * K + k) * C + c0 + 2 * cp) = pk;
    }
  }
}

__global__ __launch_bounds__(256) void cvt_cpT_kernel(
    const float* __restrict__ w_cp, ushort* __restrict__ WcpT,
    const float* __restrict__ w_cp0, ushort* __restrict__ Wcp0T) {
  __shared__ float tile[256 * 17];
  const int bid = blockIdx.x;
  if (bid < 512)
    cpT_body<1024, 16>(w_cp, WcpT, bid, tile);
  else
    cpT_body<512, 8>(w_cp0, Wcp0T, bid - 512, tile);
}

// ---------------------------------------------------------------------------
// L3: all activation transposes in ONE launch.
// seg0 feature->Ft; seg1 frame_feat->FfT; seg2 lastcls->cat[2048:2546];
// seg3 locres->cat[3570:3584] (zero pad 3572:3584).
// ---------------------------------------------------------------------------
__global__ __launch_bounds__(256) void transpose_multi_kernel(
    const float* __restrict__ feature, const float* __restrict__ frame_feat,
    const float* __restrict__ lastcls, const float* __restrict__ locres,
    ushort* __restrict__ Ft, ushort* __restrict__ FfT,
    ushort* __restrict__ cat) {
  const int bid = blockIdx.x;
  const float* src;
  ushort* dst;
  int Cr, Cw, L, rs, co, cblk, lblk, b;
  if (bid < 64) {
    src = feature; dst = Ft; Cr = 512; Cw = 512; L = 64; rs = 512; co = 0;
    cblk = bid & 7; lblk = 0; b = bid >> 3;
  } else if (bid < 320) {
    const int r = bid - 64;
    src = frame_feat; dst = FfT; Cr = 512; Cw = 512; L = 256; rs = 512; co = 0;
    cblk = r & 7; lblk = (r >> 3) & 3; b = r >> 5;
  } else if (bid < 384) {
    const int r = bid - 320;
    src = lastcls; dst = cat; Cr = 498; Cw = 498; L = 64; rs = CATP; co = 2048;
    cblk = r & 7; lblk = 0; b = r >> 3;
  } else {
    const int r = bid - 384;
    src = locres; dst = cat; Cr = 2; Cw = 14; L = 64; rs = CATP; co = 3570;
    cblk = 0; lblk = 0; b = r;
  }
  __shared__ float tile[64 * 65];
  const int c0 = cblk * 64, l0 = lblk * 64;
  for (int e = threadIdx.x; e < 4096; e += 256) {
    const int cc = e >> 6, ll = e & 63;
    const int c = c0 + cc;
    tile[cc * 65 + ll] = (c < Cr) ? src[((size_t)b * Cr + c) * L + l0 + ll] : 0.f;
  }
  __syncthreads();
  for (int e = threadIdx.x; e < 4096; e += 256) {
    const int ll = e >> 6, cc = e & 63;
    const int c = c0 + cc;
    if (c < Cw)
      dst[((size_t)b * L + l0 + ll) * rs + co + c] = f2bf(tile[cc * 65 + ll]);
  }
}

// ---------------------------------------------------------------------------
// L4/L8/L9: two-segment fused bf16 MFMA GEMM + GroupNorm + ReLU.
// Block: (64 o) x (64 t, one b); 4 waves split K; LDS reduce; in-block GN.
// Segment chosen by blockIdx.x < nblk0. grid (nblk0+nblk1, B).
// ---------------------------------------------------------------------------
__global__ __launch_bounds__(256) void gemm_gn_seg_kernel(
    int nblk0,
    const ushort* __restrict__ X0, const ushort* __restrict__ W0,
    const float* __restrict__ b0, const float* __restrict__ g0,
    const float* __restrict__ e0, int Kp0, int cs0, float* of0, int om0,
    ushort* co0, int cst0, int coff0,
    const ushort* __restrict__ X1, const ushort* __restrict__ W1,
    const float* __restrict__ b1, const float* __restrict__ g1,
    const float* __restrict__ e1, int Kp1, int cs1, float* of1, int om1,
    ushort* co1, int cst1, int coff1) {
  const int bx = blockIdx.x;
  const bool s1 = bx >= nblk0;
  const ushort* Xt = s1 ? X1 : X0;
  const ushort* Wb = s1 ? W1 : W0;
  const float* bias = s1 ? b1 : b0;
  const float* gamma = s1 ? g1 : g0;
  const float* beta = s1 ? e1 : e0;
  const int Kp = s1 ? Kp1 : Kp0;
  const int cpgShift = s1 ? cs1 : cs0;
  float* outF = s1 ? of1 : of0;
  const int outFM = s1 ? om1 : om0;
  ushort* catOut = s1 ? co1 : co0;
  const int catStride = s1 ? cst1 : cst0;
  const int chOff = s1 ? coff1 : coff0;
  const int o0 = (s1 ? bx - nblk0 : bx) * 64;

  const int b = blockIdx.y;
  const int w = threadIdx.x >> 6;
  const int lane = threadIdx.x & 63;
  const int l15 = lane & 15, l4 = lane >> 4;
  const int wk = Kp >> 2;
  const int kbeg = w * wk, kend = kbeg + wk;

  f32x4 acc[4][4] = {};
  const ushort* ap[4];
  const ushort* bp[4];
#pragma unroll
  for (int i = 0; i < 4; i++)
    ap[i] = Wb + (size_t)(o0 + i * 16 + l15) * Kp + l4 * 8;
#pragma unroll
  for (int j = 0; j < 4; j++)
    bp[j] = Xt + (size_t)(b * 64 + j * 16 + l15) * Kp + l4 * 8;

  for (int k = kbeg; k < kend; k += 32) {
    short8 a[4], x[4];
#pragma unroll
    for (int i = 0; i < 4; i++) a[i] = *(const short8*)(ap[i] + k);
#pragma unroll
    for (int j = 0; j < 4; j++) x[j] = *(const short8*)(bp[j] + k);
#pragma unroll
    for (int i = 0; i < 4; i++)
#pragma unroll
      for (int j = 0; j < 4; j++)
        acc[i][j] = __builtin_amdgcn_mfma_f32_16x16x32_bf16(a[i], x[j],
                                                            acc[i][j], 0, 0, 0);
  }

  __shared__ float red[64 * 65];
  for (int ww = 0; ww < 4; ww++) {
    __syncthreads();
    if (w == ww) {
#pragma unroll
      for (int i = 0; i < 4; i++)
#pragma unroll
        for (int j = 0; j < 4; j++)
#pragma unroll
          for (int r = 0; r < 4; r++) {
            const int m = i * 16 + l4 * 4 + r;
            const int n = j * 16 + l15;
            if (ww == 0)
              red[m * 65 + n] = acc[i][j][r] + bias[o0 + m];
            else
              red[m * 65 + n] += acc[i][j][r];
          }
    }
  }
  __syncthreads();

  const int cpg = 1 << cpgShift;
  const int ngroups = 64 >> cpgShift;
  __shared__ float rs[4], rss[4], gmean[4], grstd[4];
  for (int gi = 0; gi < ngroups; gi++) {
    float s = 0.f, ss = 0.f;
    const int nel = cpg << 6;
    for (int e = threadIdx.x; e < nel; e += 256) {
      const float v = red[((gi << cpgShift) + (e >> 6)) * 65 + (e & 63)];
      s += v;
      ss += v * v;
    }
#pragma unroll
    for (int off = 32; off > 0; off >>= 1) {
      s += __shfl_down(s, off);
      ss += __shfl_down(ss, off);
    }
    if (lane == 0) { rs[w] = s; rss[w] = ss; }
    __syncthreads();
    if (threadIdx.x == 0) {
      const float ts = rs[0] + rs[1] + rs[2] + rs[3];
      const float tss = rss[0] + rss[1] + rss[2] + rss[3];
      const float mean = ts / (float)nel;
      const float var = tss / (float)nel - mean * mean;
      gmean[gi] = mean;
      grstd[gi] = rsqrtf(var + 1e-5f);
    }
    __syncthreads();
  }

  if (outF) {
    for (int e = threadIdx.x; e < 4096; e += 256) {
      const int m = e >> 6, n = e & 63;
      const int gi = m >> cpgShift;
      const int c = o0 + m;
      float v = (red[m * 65 + n] - gmean[gi]) * grstd[gi] * gamma[c] + beta[c];
      v = fmaxf(v, 0.f);
      outF[((size_t)b * outFM + c) * 64 + n] = v;
    }
  }
  if (catOut) {
    for (int e = threadIdx.x; e < 4096; e += 256) {
      const int n = e >> 6, m = e & 63;
      const int gi = m >> cpgShift;
      const int c = o0 + m;
      float v = (red[m * 65 + n] - gmean[gi]) * grstd[gi] * gamma[c] + beta[c];
      v = fmaxf(v, 0.f);
      catOut[((size_t)(b * 64) + n) * catStride + chOff + c] = f2bf(v);
    }
  }
}

// ---------------------------------------------------------------------------
// L5: dual BoundaryMaxPooling on transposed bf16. z=0: FlrT; z=1: FfT.
// ---------------------------------------------------------------------------
template <int C, int L>
__device__ void bmp_body(const ushort* __restrict__ Xt,
                         const int* __restrict__ segs, ushort* __restrict__ Y,
                         int rowStride, int chOff, float2 (*pmax)[512]) {
  constexpr int C2 = C / 2;
  constexpr int P2 = C2 / 2;
  constexpr int CH = P2 / 64;
  const int t = blockIdx.x;
  const int b = blockIdx.y;
  const int w = threadIdx.x >> 6;
  const int lane = threadIdx.x & 63;
  const int* sg = segs + ((size_t)b * 64 + t) * 4;
  const ushort* Xb = Xt + (size_t)b * L * C;
#pragma unroll
  for (int h = 0; h < 2; h++) {
    const int s = min(max(sg[2 * h], 0), L - 1);
    const int e = max(min(max(sg[2 * h + 1], 0), L - 1), s);
#pragma unroll
    for (int q = 0; q < CH; q++) {
      const int p = q * 64 + lane;
      const ushort* base = Xb + h * C2 + 2 * p;
      float a0 = -INFINITY, a1 = -INFINITY;
      float c0 = -INFINITY, c1 = -INFINITY;
      int l = s + w;
      for (; l + 4 <= e; l += 8) {
        const unsigned u0 = *(const unsigned*)(base + (size_t)l * C);
        const unsigned u1 = *(const unsigned*)(base + (size_t)(l + 4) * C);
        a0 = fmaxf(a0, bf2f(u0 & 0xffffu));
        a1 = fmaxf(a1, bf2f(u0 >> 16));
        c0 = fmaxf(c0, bf2f(u1 & 0xffffu));
        c1 = fmaxf(c1, bf2f(u1 >> 16));
      }
      if (l <= e) {
        const unsigned u0 = *(const unsigned*)(base + (size_t)l * C);
        a0 = fmaxf(a0, bf2f(u0 & 0xffffu));
        a1 = fmaxf(a1, bf2f(u0 >> 16));
      }
      pmax[w][h * P2 + p] = make_float2(fmaxf(a0, c0), fmaxf(a1, c1));
    }
  }
  __syncthreads();
  for (int idx = threadIdx.x; idx < 2 * P2; idx += 256) {
    float2 m = pmax[0][idx];
#pragma unroll
    for (int ww = 1; ww < 4; ww++) {
      const float2 v = pmax[ww][idx];
      m.x = fmaxf(m.x, v.x);
      m.y = fmaxf(m.y, v.y);
    }
    const unsigned o = (unsigned)f2bf(m.x) | ((unsigned)f2bf(m.y) << 16);
    *(unsigned*)(Y + ((size_t)(b * 64) + t) * rowStride + chOff + 2 * idx) = o;
  }
}

__global__ __launch_bounds__(256) void bmp_dual_kernel(
    const ushort* __restrict__ FlrT, const int* __restrict__ segments,
    ushort* __restrict__ cat, const ushort* __restrict__ FfT,
    const int* __restrict__ frame_segs, ushort* __restrict__ XbmpT) {
  __shared__ float2 pm[4][512];
  if (blockIdx.z == 0)
    bmp_body<1024, 64>(FlrT, segments, cat, CATP, 512, pm);
  else
    bmp_body<512, 256>(FfT, frame_segs, XbmpT, 512, 0, pm);
}

// ---------------------------------------------------------------------------
// L6: dual anchor-conv MFMA with FUSED gather. A rows read directly from the
// transposed bf16 feature (FlrT/FfT) via the per-(t,k) anchor index; weights
// in [o][k][c] layout so the reduction axis kk = k*Cin + c matches.
// Each wave handles one k tap (k = kz*4 + w); LDS cross-wave reduce sums the
// 4 taps; P partials as before. grid (8 n-tiles, 8 b, 6): z<4 big kz=z,
// z>=4 small kz=z-4.
// ---------------------------------------------------------------------------
template <int Kf, int L, int Cin>
__device__ void anchor_mfma_body(const ushort* __restrict__ src,
                                 const int* __restrict__ anc,
                                 const ushort* __restrict__ Wt,
                                 float* __restrict__ P, int kz, float* red) {
  const int n0 = blockIdx.x * 64;
  const int b = blockIdx.y;
  const int w = threadIdx.x >> 6;
  const int lane = threadIdx.x & 63;
  const int l15 = lane & 15, l4 = lane >> 4;
  const int k = kz * 4 + w;

  const ushort* rp[4];
#pragma unroll
  for (int i = 0; i < 4; i++) {
    const int t = i * 16 + l15;
    const int a0 = anc[((size_t)b * 64 + t) * 2 + 0];
    const int a1 = anc[((size_t)b * 64 + t) * 2 + 1];
    const int left = min(max(a0, 0), L);
    const int right = min(max(a1, 0), L);
    const int seglen = right + 1 - left;
    const int ix = min(max(left + (k * seglen) / Kf, 0), L - 1);
    rp[i] = src + ((size_t)b * L + ix) * Cin + l4 * 8;
  }
  const ushort* wp[4];
#pragma unroll
  for (int j = 0; j < 4; j++)
    wp[j] = Wt + ((size_t)(n0 + j * 16 + l15) * Kf + k) * Cin + l4 * 8;

  f32x4 acc[4][4] = {};
  for (int c0 = 0; c0 < Cin; c0 += 32) {
    short8 a[4], bb[4];
#pragma unroll
    for (int i = 0; i < 4; i++) a[i] = *(const short8*)(rp[i] + c0);
#pragma unroll
    for (int j = 0; j < 4; j++) bb[j] = *(const short8*)(wp[j] + c0);
#pragma unroll
    for (int i = 0; i < 4; i++)
#pragma unroll
      for (int j = 0; j < 4; j++)
        acc[i][j] = __builtin_amdgcn_mfma_f32_16x16x32_bf16(a[i], bb[j],
                                                            acc[i][j], 0, 0, 0);
  }

  for (int ww = 0; ww < 4; ww++) {
    __syncthreads();
    if (w == ww) {
#pragma unroll
      for (int i = 0; i < 4; i++)
#pragma unroll
        for (int j = 0; j < 4; j++)
#pragma unroll
          for (int r = 0; r < 4; r++) {
            const int m = i * 16 + l4 * 4 + r;
            const int n = j * 16 + l15;
            if (ww == 0)
              red[m * 65 + n] = acc[i][j][r];
            else
              red[m * 65 + n] += acc[i][j][r];
          }
    }
  }
  __syncthreads();
  float* Pp = P + (((size_t)kz * BB + b) * 512 + n0) * 64;
  for (int e = threadIdx.x; e < 4096; e += 256) {
    const int n = e >> 6, m = e & 63;
    Pp[e] = red[m * 65 + n];
  }
}

__global__ __launch_bounds__(256) void anchor_mfma_dual_kernel(
    const ushort* __restrict__ FlrT, const int* __restrict__ anchor,
    const ushort* __restrict__ WcpT, float* __restrict__ P1,
    const ushort* __restrict__ FfT, const int* __restrict__ frame_anchor,
    const ushort* __restrict__ Wcp0T, float* __restrict__ P0) {
  __shared__ float red[64 * 65];
  const int z = blockIdx.z;
  if (z < 4)
    anchor_mfma_body<16, 64, 1024>(FlrT, anchor, WcpT, P1, z, red);
  else
    anchor_mfma_body<8, 256, 512>(FfT, frame_anchor, Wcp0T, P0, z - 4, red);
}

// ---------------------------------------------------------------------------
// L7: dual split-K reduce + valid mask + bias -> bf16 transposed rows.
// grid (8, 8, 2): z=0 big -> cat[2546:3058]; z=1 small -> FconT.
// ---------------------------------------------------------------------------
__device__ void anchor_reduce_body(const float* __restrict__ P, int ks,
                                   const float* __restrict__ bias,
                                   const int* __restrict__ anc, int L,
                                   ushort* __restrict__ Y, int rowStride,
                                   int chOff, float* tile, float* sval) {
  const int o0 = blockIdx.x * 64;
  const int b = blockIdx.y;
  if (threadIdx.x < 64) {
    const int t = threadIdx.x;
    const int a0 = anc[((size_t)b * 64 + t) * 2 + 0];
    const int a1 = anc[((size_t)b * 64 + t) * 2 + 1];
    const int left = min(max(a0, 0), L);
    const int right = min(max(a1, 0), L);
    sval[t] = (right > left) ? 1.f : 0.f;
  }
  __syncthreads();
  for (int e = threadIdx.x; e < 4096; e += 256) {
    const int nl = e >> 6, m = e & 63;
    const int n = o0 + nl;
    float s = 0.f;
    for (int z = 0; z < ks; z++)
      s += P[(((size_t)z * BB + b) * 512 + n) * 64 + m];
    tile[nl * 65 + m] = s * sval[m] + bias[n];
  }
  __syncthreads();
  for (int e = threadIdx.x; e < 4096; e += 256) {
    const int m = e >> 6, nl = e & 63;
    Y[((size_t)(b * 64) + m) * rowStride + chOff + o0 + nl] =
        f2bf(tile[nl * 65 + m]);
  }
}

__global__ __launch_bounds__(256) void anchor_reduce_dual_kernel(
    const float* __restrict__ P1, const float* __restrict__ b_cp,
    const int* __restrict__ anchor, ushort* __restrict__ cat,
    const float* __restrict__ P0, const float* __restrict__ b_cp0,
    const int* __restrict__ frame_anchor, ushort* __restrict__ FconT) {
  __shared__ float tile[64 * 65];
  __shared__ float sval[64];
  if (blockIdx.z == 0)
    anchor_reduce_body(P1, 4, b_cp, anchor, 64, cat, CATP, 2546, tile, sval);
  else
    anchor_reduce_body(P0, 2, b_cp0, frame_anchor, 256, FconT, 512, 0, tile, sval);
}

extern "C" void kernel_launch(void* const* d_in, const int* in_sizes, int n_in,
                              void* d_out, int out_size, void* d_ws,
                              size_t ws_size, hipStream_t stream) {
  const float* feature      = (const float*)d_in[0];
  const float* frame_feat   = (const float*)d_in[1];
  const int*   segments     = (const int*)d_in[2];
  const int*   frame_segs   = (const int*)d_in[3];
  const float* feat_lastcls = (const float*)d_in[4];
  const int*   anchor       = (const int*)d_in[5];
  const int*   frame_anchor = (const int*)d_in[6];
  const float* locres       = (const float*)d_in[8];
  const float* w_cur  = (const float*)d_in[9];
  const float* b_cur  = (const float*)d_in[10];
  const float* g_cur  = (const float*)d_in[11];
  const float* be_cur = (const float*)d_in[12];
  const float* w_lr   = (const float*)d_in[13];
  const float* b_lr   = (const float*)d_in[14];
  const float* g_lr   = (const float*)d_in[15];
  const float* be_lr  = (const float*)d_in[16];
  const float* w_roi  = (const float*)d_in[17];
  const float* b_roi  = (const float*)d_in[18];
  const float* g_roi  = (const float*)d_in[19];
  const float* be_roi = (const float*)d_in[20];
  const float* w_cp   = (const float*)d_in[21];  // [512,1024,16]
  const float* b_cp   = (const float*)d_in[22];
  const float* w_cp0  = (const float*)d_in[23];  // [512,512,8]
  const float* b_cp0  = (const float*)d_in[24];
  const float* w_prop = (const float*)d_in[25];  // [512,3572]
  const float* b_prop = (const float*)d_in[26];
  const float* g_prop = (const float*)d_in[27];
  const float* be_prop= (const float*)d_in[28];

  float* out_main = (float*)d_out;                  // [8,512,64]
  float* feat_lr  = (float*)d_out + BB * 512 * 64;  // [8,1024,64]

  // workspace layout (ushort units)
  ushort* cat_t  = (ushort*)d_ws;             // 1,835,008
  ushort* Ft     = cat_t + 1835008;           // 262,144
  ushort* XbmpT  = Ft + 262144;               // 262,144
  ushort* FconT  = XbmpT + 262144;            // 262,144
  ushort* Wcomb  = FconT + 262144;            // 786,432 [1536][512]
  ushort* Wroi   = Wcomb + 786432;            // 262,144
  ushort* Wprop  = Wroi + 262144;             // 1,835,008
  ushort* WcpT   = Wprop + 1835008;           // 8,388,608 [512][16][1024]
  ushort* Wcp0T  = WcpT + 8388608;            // 2,097,152 [512][8][512]
  ushort* FlrT   = Wcp0T + 2097152;           // 524,288  [8*64][1024]
  ushort* FfT    = FlrT + 524288;             // 1,048,576 [8*256][512]
  float*  P1     = (float*)(FfT + 1048576);   // 1,048,576 f
  float*  P0     = P1 + 1048576;              // 524,288 f
  // total ~41.4 MB

  // L1: flat weight converts + w_prop pad
  cvt_weights_kernel<<<4608, 256, 0, stream>>>(
      (const float4*)w_cur, (const float4*)w_lr, (const float4*)w_roi,
      (uint2*)Wcomb, (uint2*)Wroi, w_prop, (unsigned*)Wprop);

  // L2: conv weight transpose converts
  cvt_cpT_kernel<<<1024, 256, 0, stream>>>(w_cp, WcpT, w_cp0, Wcp0T);

  // L3: activation transposes (+ lastcls & locres into cat)
  transpose_multi_kernel<<<392, 256, 0, stream>>>(
      feature, frame_feat, feat_lastcls, locres, Ft, FfT, cat_t);

  // L4: fm_short -> cat[1536:2048]  |  feat_lr -> out + FlrT
  gemm_gn_seg_kernel<<<dim3(24, BB), 256, 0, stream>>>(
      8,
      Ft, Wcomb, b_cur, g_cur, be_cur, 512, 4, nullptr, 0, cat_t, CATP, 1536,
      Ft, Wcomb + 512 * 512, b_lr, g_lr, be_lr, 512, 5, feat_lr, 1024, FlrT,
      1024, 0);

  // L5: prop_feature -> cat[512:1536]  |  bmp(frame) -> XbmpT
  bmp_dual_kernel<<<dim3(64, BB, 2), 256, 0, stream>>>(
      FlrT, segments, cat_t, FfT, frame_segs, XbmpT);

  // L6: both anchor convs (fused gather) -> P1 / P0
  anchor_mfma_dual_kernel<<<dim3(8, BB, 6), 256, 0, stream>>>(
      FlrT, anchor, WcpT, P1, FfT, frame_anchor, Wcp0T, P0);

  // L7: split-K reduce -> cat[2546:3058] | FconT
  anchor_reduce_dual_kernel<<<dim3(8, BB, 2), 256, 0, stream>>>(
      P1, b_cp, anchor, cat_t, P0, b_cp0, frame_anchor, FconT);

  // L8: prop_roi -> cat[0:512]  |  prop_con -> cat[3058:3570]
  gemm_gn_seg_kernel<<<dim3(16, BB), 256, 0, stream>>>(
      8,
      XbmpT, Wroi, b_roi, g_roi, be_roi, 512, 4, nullptr, 0, cat_t, CATP, 0,
      FconT, Wroi, b_roi, g_roi, be_roi, 512, 4, nullptr, 0, cat_t, CATP, 3058);

  // L9: final projection -> out_main
  gemm_gn_seg_kernel<<<dim3(8, BB), 256, 0, stream>>>(
      8,
      cat_t, Wprop, b_prop, g_prop, be_prop, CATP, 4, out_main, 512, nullptr,
      CATP, 0,
      cat_t, Wprop, b_prop, g_prop, be_prop, CATP, 4, nullptr, 0, nullptr,
      CATP, 0);
}

// Round 7
// 308.621 us; speedup vs baseline: 1.4997x; 1.0109x over previous
//
#include <hip/hip_runtime.h>
#include <math.h>

#define BB 8
#define CATP 3584   // padded cat K (3572 -> 3584, zeros)
#define CAT_REAL 3572

typedef __attribute__((ext_vector_type(8))) short short8;
typedef __attribute__((ext_vector_type(4))) float f32x4;

__device__ inline ushort f2bf(float f) {
  union { float f; unsigned u; } x;
  x.f = f;
  return (ushort)((x.u + 0x7FFFu + ((x.u >> 16) & 1u)) >> 16);
}
__device__ inline float bf2f(unsigned us) {
  union { unsigned u; float f; } x;
  x.u = us << 16;
  return x.f;
}

// ---------------------------------------------------------------------------
// L1: dense-GEMM weights -> bf16 in MFMA FRAGMENT order.
// Fragment layout (shorts): (((ot*(Kp/32) + kc)*4 + i)*64 + l4*16 + l15)*8 + kk
// where o = ot*64 + i*16 + l15, k = kc*32 + l4*8 + kk.
// Thread = one (o, k8): reads 8 consecutive f32, writes one 16B chunk.
// Segments: Wcomb (w_cur 512 + w_lr 1024 rows, Kp=512), Wroi (512, Kp=512),
// Wprop (512, Kp=3584 padded from 3572).
// ---------------------------------------------------------------------------
__global__ __launch_bounds__(256) void cvt_wfrag_kernel(
    const float* __restrict__ w_cur, const float* __restrict__ w_lr,
    const float* __restrict__ w_roi, const float* __restrict__ w_prop,
    ushort* __restrict__ Wcomb, ushort* __restrict__ Wroi,
    ushort* __restrict__ Wprop) {
  const int i = blockIdx.x * 256 + threadIdx.x;
  const float* src;
  ushort* dst;
  int o, k8, Kc;  // Kc = Kp/32
  bool pad = false;
  if (i < 98304) {
    o = i >> 6; k8 = i & 63; Kc = 16;
    src = (o < 512) ? (w_cur + (size_t)o * 512) : (w_lr + (size_t)(o - 512) * 512);
    dst = Wcomb;
  } else if (i < 131072) {
    const int r = i - 98304;
    o = r >> 6; k8 = r & 63; Kc = 16;
    src = w_roi + (size_t)o * 512;
    dst = Wroi;
  } else {
    const int r = i - 131072;
    if (r >= 229376) return;
    o = r / 448; k8 = r % 448; Kc = 112;
    src = w_prop + (size_t)o * CAT_REAL;
    dst = Wprop;
    pad = true;
  }
  const int k = k8 * 8;
  float v[8];
  if (pad) {
#pragma unroll
    for (int q = 0; q < 8; q++) v[q] = (k + q < CAT_REAL) ? src[k + q] : 0.f;
  } else {
    const float4 f0 = *(const float4*)(src + k);
    const float4 f1 = *(const float4*)(src + k + 4);
    v[0] = f0.x; v[1] = f0.y; v[2] = f0.z; v[3] = f0.w;
    v[4] = f1.x; v[5] = f1.y; v[6] = f1.z; v[7] = f1.w;
  }
  uint4 pk;
  pk.x = (unsigned)f2bf(v[0]) | ((unsigned)f2bf(v[1]) << 16);
  pk.y = (unsigned)f2bf(v[2]) | ((unsigned)f2bf(v[3]) << 16);
  pk.z = (unsigned)f2bf(v[4]) | ((unsigned)f2bf(v[5]) << 16);
  pk.w = (unsigned)f2bf(v[6]) | ((unsigned)f2bf(v[7]) << 16);
  const int ot = o >> 6, ii = (o >> 4) & 3, l15 = o & 15;
  const int kc = k8 >> 2, l4 = k8 & 3;
  const size_t flat =
      ((((size_t)ot * Kc + kc) * 4 + ii) * 64 + l4 * 16 + l15) * 8;
  *(uint4*)(dst + flat) = pk;
}

// ---------------------------------------------------------------------------
// L2: anchor conv weights W [O][C][K] f32 -> bf16 fragment order:
// (((nt*Kf + k)*(Cin/32) + cc)*4 + j)*512 + (l4*16 + l15)*8 + kk
// where o = nt*64 + j*16 + l15, c = cc*32 + l4*8 + kk. One block per o.
// ---------------------------------------------------------------------------
template <int Cin, int Kf>
__device__ void cpT_body(const float* __restrict__ W, ushort* __restrict__ D,
                         int o, float* tile /* 256*(Kf+1) */) {
  const int nt = o >> 6, j = (o >> 4) & 3, l15 = o & 15;
  for (int c0 = 0; c0 < Cin; c0 += 256) {
    __syncthreads();
    for (int e = threadIdx.x; e < 256 * Kf; e += 256) {
      const int c = e / Kf, k = e % Kf;
      tile[c * (Kf + 1) + k] = W[((size_t)o * Cin + c0) * Kf + e];
    }
    __syncthreads();
    for (int e = threadIdx.x; e < Kf * 32; e += 256) {
      const int k = e >> 5, c8 = e & 31;
      const int cl = c8 * 8;
      const int c = c0 + cl;
      uint4 pk;
      pk.x = (unsigned)f2bf(tile[(cl + 0) * (Kf + 1) + k]) |
             ((unsigned)f2bf(tile[(cl + 1) * (Kf + 1) + k]) << 16);
      pk.y = (unsigned)f2bf(tile[(cl + 2) * (Kf + 1) + k]) |
             ((unsigned)f2bf(tile[(cl + 3) * (Kf + 1) + k]) << 16);
      pk.z = (unsigned)f2bf(tile[(cl + 4) * (Kf + 1) + k]) |
             ((unsigned)f2bf(tile[(cl + 5) * (Kf + 1) + k]) << 16);
      pk.w = (unsigned)f2bf(tile[(cl + 6) * (Kf + 1) + k]) |
             ((unsigned)f2bf(tile[(cl + 7) * (Kf + 1) + k]) << 16);
      const int cc = c >> 5, l4 = (c >> 3) & 3;
      const size_t flat =
          ((((size_t)nt * Kf + k) * (Cin >> 5) + cc) * 4 + j) * 512 +
          (l4 * 16 + l15) * 8;
      *(uint4*)(D + flat) = pk;
    }
  }
}

__global__ __launch_bounds__(256) void cvt_cpT_kernel(
    const float* __restrict__ w_cp, ushort* __restrict__ WcpT,
    const float* __restrict__ w_cp0, ushort* __restrict__ Wcp0T) {
  __shared__ float tile[256 * 17];
  const int bid = blockIdx.x;
  if (bid < 512)
    cpT_body<1024, 16>(w_cp, WcpT, bid, tile);
  else
    cpT_body<512, 8>(w_cp0, Wcp0T, bid - 512, tile);
}

// ---------------------------------------------------------------------------
// L3: all activation transposes in ONE launch.
// ---------------------------------------------------------------------------
__global__ __launch_bounds__(256) void transpose_multi_kernel(
    const float* __restrict__ feature, const float* __restrict__ frame_feat,
    const float* __restrict__ lastcls, const float* __restrict__ locres,
    ushort* __restrict__ Ft, ushort* __restrict__ FfT,
    ushort* __restrict__ cat) {
  const int bid = blockIdx.x;
  const float* src;
  ushort* dst;
  int Cr, Cw, L, rs, co, cblk, lblk, b;
  if (bid < 64) {
    src = feature; dst = Ft; Cr = 512; Cw = 512; L = 64; rs = 512; co = 0;
    cblk = bid & 7; lblk = 0; b = bid >> 3;
  } else if (bid < 320) {
    const int r = bid - 64;
    src = frame_feat; dst = FfT; Cr = 512; Cw = 512; L = 256; rs = 512; co = 0;
    cblk = r & 7; lblk = (r >> 3) & 3; b = r >> 5;
  } else if (bid < 384) {
    const int r = bid - 320;
    src = lastcls; dst = cat; Cr = 498; Cw = 498; L = 64; rs = CATP; co = 2048;
    cblk = r & 7; lblk = 0; b = r >> 3;
  } else {
    const int r = bid - 384;
    src = locres; dst = cat; Cr = 2; Cw = 14; L = 64; rs = CATP; co = 3570;
    cblk = 0; lblk = 0; b = r;
  }
  __shared__ float tile[64 * 65];
  const int c0 = cblk * 64, l0 = lblk * 64;
  for (int e = threadIdx.x; e < 4096; e += 256) {
    const int cc = e >> 6, ll = e & 63;
    const int c = c0 + cc;
    tile[cc * 65 + ll] = (c < Cr) ? src[((size_t)b * Cr + c) * L + l0 + ll] : 0.f;
  }
  __syncthreads();
  for (int e = threadIdx.x; e < 4096; e += 256) {
    const int ll = e >> 6, cc = e & 63;
    const int c = c0 + cc;
    if (c < Cw)
      dst[((size_t)b * L + l0 + ll) * rs + co + c] = f2bf(tile[cc * 65 + ll]);
  }
}

// ---------------------------------------------------------------------------
// L4/L8/L9: two-segment fused bf16 MFMA GEMM + GroupNorm + ReLU.
// Weights in FRAGMENT order (coalesced 1KB bursts); activations row-major.
// ---------------------------------------------------------------------------
__global__ __launch_bounds__(256) void gemm_gn_seg_kernel(
    int nblk0,
    const ushort* __restrict__ X0, const ushort* __restrict__ W0,
    const float* __restrict__ b0, const float* __restrict__ g0,
    const float* __restrict__ e0, int Kp0, int cs0, float* of0, int om0,
    ushort* co0, int cst0, int coff0,
    const ushort* __restrict__ X1, const ushort* __restrict__ W1,
    const float* __restrict__ b1, const float* __restrict__ g1,
    const float* __restrict__ e1, int Kp1, int cs1, float* of1, int om1,
    ushort* co1, int cst1, int coff1) {
  const int bx = blockIdx.x;
  const bool s1 = bx >= nblk0;
  const ushort* Xt = s1 ? X1 : X0;
  const ushort* Wb = s1 ? W1 : W0;
  const float* bias = s1 ? b1 : b0;
  const float* gamma = s1 ? g1 : g0;
  const float* beta = s1 ? e1 : e0;
  const int Kp = s1 ? Kp1 : Kp0;
  const int cpgShift = s1 ? cs1 : cs0;
  float* outF = s1 ? of1 : of0;
  const int outFM = s1 ? om1 : om0;
  ushort* catOut = s1 ? co1 : co0;
  const int catStride = s1 ? cst1 : cst0;
  const int chOff = s1 ? coff1 : coff0;
  const int o0 = (s1 ? bx - nblk0 : bx) * 64;

  const int b = blockIdx.y;
  const int w = threadIdx.x >> 6;
  const int lane = threadIdx.x & 63;
  const int l15 = lane & 15, l4 = lane >> 4;
  const int wk = Kp >> 2;
  const int kbeg = w * wk, kend = kbeg + wk;

  f32x4 acc[4][4] = {};
  const ushort* wbase = Wb + (size_t)(o0 >> 6) * (Kp >> 5) * 2048 + lane * 8;
  const ushort* bp[4];
#pragma unroll
  for (int j = 0; j < 4; j++)
    bp[j] = Xt + (size_t)(b * 64 + j * 16 + l15) * Kp + l4 * 8;

  for (int k = kbeg; k < kend; k += 32) {
    const int kc = k >> 5;
    short8 a[4], x[4];
#pragma unroll
    for (int i = 0; i < 4; i++)
      a[i] = *(const short8*)(wbase + ((size_t)kc * 4 + i) * 512);
#pragma unroll
    for (int j = 0; j < 4; j++) x[j] = *(const short8*)(bp[j] + k);
#pragma unroll
    for (int i = 0; i < 4; i++)
#pragma unroll
      for (int j = 0; j < 4; j++)
        acc[i][j] = __builtin_amdgcn_mfma_f32_16x16x32_bf16(a[i], x[j],
                                                            acc[i][j], 0, 0, 0);
  }

  __shared__ float red[64 * 65];
  for (int ww = 0; ww < 4; ww++) {
    __syncthreads();
    if (w == ww) {
#pragma unroll
      for (int i = 0; i < 4; i++)
#pragma unroll
        for (int j = 0; j < 4; j++)
#pragma unroll
          for (int r = 0; r < 4; r++) {
            const int m = i * 16 + l4 * 4 + r;
            const int n = j * 16 + l15;
            if (ww == 0)
              red[m * 65 + n] = acc[i][j][r] + bias[o0 + m];
            else
              red[m * 65 + n] += acc[i][j][r];
          }
    }
  }
  __syncthreads();

  const int cpg = 1 << cpgShift;
  const int ngroups = 64 >> cpgShift;
  __shared__ float rs[4], rss[4], gmean[4], grstd[4];
  for (int gi = 0; gi < ngroups; gi++) {
    float s = 0.f, ss = 0.f;
    const int nel = cpg << 6;
    for (int e = threadIdx.x; e < nel; e += 256) {
      const float v = red[((gi << cpgShift) + (e >> 6)) * 65 + (e & 63)];
      s += v;
      ss += v * v;
    }
#pragma unroll
    for (int off = 32; off > 0; off >>= 1) {
      s += __shfl_down(s, off);
      ss += __shfl_down(ss, off);
    }
    if (lane == 0) { rs[w] = s; rss[w] = ss; }
    __syncthreads();
    if (threadIdx.x == 0) {
      const float ts = rs[0] + rs[1] + rs[2] + rs[3];
      const float tss = rss[0] + rss[1] + rss[2] + rss[3];
      const float mean = ts / (float)nel;
      const float var = tss / (float)nel - mean * mean;
      gmean[gi] = mean;
      grstd[gi] = rsqrtf(var + 1e-5f);
    }
    __syncthreads();
  }

  if (outF) {
    for (int e = threadIdx.x; e < 4096; e += 256) {
      const int m = e >> 6, n = e & 63;
      const int gi = m >> cpgShift;
      const int c = o0 + m;
      float v = (red[m * 65 + n] - gmean[gi]) * grstd[gi] * gamma[c] + beta[c];
      v = fmaxf(v, 0.f);
      outF[((size_t)b * outFM + c) * 64 + n] = v;
    }
  }
  if (catOut) {
    for (int e = threadIdx.x; e < 4096; e += 256) {
      const int n = e >> 6, m = e & 63;
      const int gi = m >> cpgShift;
      const int c = o0 + m;
      float v = (red[m * 65 + n] - gmean[gi]) * grstd[gi] * gamma[c] + beta[c];
      v = fmaxf(v, 0.f);
      catOut[((size_t)(b * 64) + n) * catStride + chOff + c] = f2bf(v);
    }
  }
}

// ---------------------------------------------------------------------------
// L5: dual BoundaryMaxPooling on transposed bf16.
// ---------------------------------------------------------------------------
template <int C, int L>
__device__ void bmp_body(const ushort* __restrict__ Xt,
                         const int* __restrict__ segs, ushort* __restrict__ Y,
                         int rowStride, int chOff, float2 (*pmax)[512]) {
  constexpr int C2 = C / 2;
  constexpr int P2 = C2 / 2;
  constexpr int CH = P2 / 64;
  const int t = blockIdx.x;
  const int b = blockIdx.y;
  const int w = threadIdx.x >> 6;
  const int lane = threadIdx.x & 63;
  const int* sg = segs + ((size_t)b * 64 + t) * 4;
  const ushort* Xb = Xt + (size_t)b * L * C;
#pragma unroll
  for (int h = 0; h < 2; h++) {
    const int s = min(max(sg[2 * h], 0), L - 1);
    const int e = max(min(max(sg[2 * h + 1], 0), L - 1), s);
#pragma unroll
    for (int q = 0; q < CH; q++) {
      const int p = q * 64 + lane;
      const ushort* base = Xb + h * C2 + 2 * p;
      float a0 = -INFINITY, a1 = -INFINITY;
      float c0 = -INFINITY, c1 = -INFINITY;
      int l = s + w;
      for (; l + 4 <= e; l += 8) {
        const unsigned u0 = *(const unsigned*)(base + (size_t)l * C);
        const unsigned u1 = *(const unsigned*)(base + (size_t)(l + 4) * C);
        a0 = fmaxf(a0, bf2f(u0 & 0xffffu));
        a1 = fmaxf(a1, bf2f(u0 >> 16));
        c0 = fmaxf(c0, bf2f(u1 & 0xffffu));
        c1 = fmaxf(c1, bf2f(u1 >> 16));
      }
      if (l <= e) {
        const unsigned u0 = *(const unsigned*)(base + (size_t)l * C);
        a0 = fmaxf(a0, bf2f(u0 & 0xffffu));
        a1 = fmaxf(a1, bf2f(u0 >> 16));
      }
      pmax[w][h * P2 + p] = make_float2(fmaxf(a0, c0), fmaxf(a1, c1));
    }
  }
  __syncthreads();
  for (int idx = threadIdx.x; idx < 2 * P2; idx += 256) {
    float2 m = pmax[0][idx];
#pragma unroll
    for (int ww = 1; ww < 4; ww++) {
      const float2 v = pmax[ww][idx];
      m.x = fmaxf(m.x, v.x);
      m.y = fmaxf(m.y, v.y);
    }
    const unsigned o = (unsigned)f2bf(m.x) | ((unsigned)f2bf(m.y) << 16);
    *(unsigned*)(Y + ((size_t)(b * 64) + t) * rowStride + chOff + 2 * idx) = o;
  }
}

__global__ __launch_bounds__(256) void bmp_dual_kernel(
    const ushort* __restrict__ FlrT, const int* __restrict__ segments,
    ushort* __restrict__ cat, const ushort* __restrict__ FfT,
    const int* __restrict__ frame_segs, ushort* __restrict__ XbmpT) {
  __shared__ float2 pm[4][512];
  if (blockIdx.z == 0)
    bmp_body<1024, 64>(FlrT, segments, cat, CATP, 512, pm);
  else
    bmp_body<512, 256>(FfT, frame_segs, XbmpT, 512, 0, pm);
}

// ---------------------------------------------------------------------------
// L6: dual anchor-conv MFMA, fused gather, FRAGMENT-ordered weights,
// split-K (k-taps across waves) AND split-C (z parity) for concurrency.
// grid (8 n-tiles, 8 b, 12): z<8 big (slice z), z>=8 small (slice z-8).
// ---------------------------------------------------------------------------
template <int Kf, int L, int Cin>
__device__ void anchor_mfma_body(const ushort* __restrict__ src,
                                 const int* __restrict__ anc,
                                 const ushort* __restrict__ Wt,
                                 float* __restrict__ P, int slice, float* red) {
  const int nt = blockIdx.x;
  const int b = blockIdx.y;
  const int w = threadIdx.x >> 6;
  const int lane = threadIdx.x & 63;
  const int l15 = lane & 15, l4 = lane >> 4;
  const int kz = slice >> 1, chalf = slice & 1;
  const int k = kz * 4 + w;
  const int cbase = chalf * (Cin / 2);

  const ushort* rp[4];
#pragma unroll
  for (int i = 0; i < 4; i++) {
    const int t = i * 16 + l15;
    const int a0 = anc[((size_t)b * 64 + t) * 2 + 0];
    const int a1 = anc[((size_t)b * 64 + t) * 2 + 1];
    const int left = min(max(a0, 0), L);
    const int right = min(max(a1, 0), L);
    const int seglen = right + 1 - left;
    const int ix = min(max(left + (k * seglen) / Kf, 0), L - 1);
    rp[i] = src + ((size_t)b * L + ix) * Cin + cbase + l4 * 8;
  }
  const ushort* wb = Wt + (size_t)(nt * Kf + k) * (Cin >> 5) * 2048 + lane * 8;

  f32x4 acc[4][4] = {};
  for (int c0 = 0; c0 < Cin / 2; c0 += 32) {
    const int cc = (cbase + c0) >> 5;
    short8 a[4], bb[4];
#pragma unroll
    for (int i = 0; i < 4; i++) a[i] = *(const short8*)(rp[i] + c0);
#pragma unroll
    for (int j = 0; j < 4; j++)
      bb[j] = *(const short8*)(wb + ((size_t)cc * 4 + j) * 512);
#pragma unroll
    for (int i = 0; i < 4; i++)
#pragma unroll
      for (int j = 0; j < 4; j++)
        acc[i][j] = __builtin_amdgcn_mfma_f32_16x16x32_bf16(a[i], bb[j],
                                                            acc[i][j], 0, 0, 0);
  }

  for (int ww = 0; ww < 4; ww++) {
    __syncthreads();
    if (w == ww) {
#pragma unroll
      for (int i = 0; i < 4; i++)
#pragma unroll
        for (int j = 0; j < 4; j++)
#pragma unroll
          for (int r = 0; r < 4; r++) {
            const int m = i * 16 + l4 * 4 + r;
            const int n = j * 16 + l15;
            if (ww == 0)
              red[m * 65 + n] = acc[i][j][r];
            else
              red[m * 65 + n] += acc[i][j][r];
          }
    }
  }
  __syncthreads();
  float* Pp = P + (((size_t)slice * BB + b) * 512 + nt * 64) * 64;
  for (int e = threadIdx.x; e < 4096; e += 256) {
    const int n = e >> 6, m = e & 63;
    Pp[e] = red[m * 65 + n];
  }
}

__global__ __launch_bounds__(256) void anchor_mfma_dual_kernel(
    const ushort* __restrict__ FlrT, const int* __restrict__ anchor,
    const ushort* __restrict__ WcpT, float* __restrict__ P1,
    const ushort* __restrict__ FfT, const int* __restrict__ frame_anchor,
    const ushort* __restrict__ Wcp0T, float* __restrict__ P0) {
  __shared__ float red[64 * 65];
  const int z = blockIdx.z;
  if (z < 8)
    anchor_mfma_body<16, 64, 1024>(FlrT, anchor, WcpT, P1, z, red);
  else
    anchor_mfma_body<8, 256, 512>(FfT, frame_anchor, Wcp0T, P0, z - 8, red);
}

// ---------------------------------------------------------------------------
// L7: dual split-K reduce + valid mask + bias -> bf16 transposed rows.
// ---------------------------------------------------------------------------
__device__ void anchor_reduce_body(const float* __restrict__ P, int ks,
                                   const float* __restrict__ bias,
                                   const int* __restrict__ anc, int L,
                                   ushort* __restrict__ Y, int rowStride,
                                   int chOff, float* tile, float* sval) {
  const int o0 = blockIdx.x * 64;
  const int b = blockIdx.y;
  if (threadIdx.x < 64) {
    const int t = threadIdx.x;
    const int a0 = anc[((size_t)b * 64 + t) * 2 + 0];
    const int a1 = anc[((size_t)b * 64 + t) * 2 + 1];
    const int left = min(max(a0, 0), L);
    const int right = min(max(a1, 0), L);
    sval[t] = (right > left) ? 1.f : 0.f;
  }
  __syncthreads();
  for (int e = threadIdx.x; e < 4096; e += 256) {
    const int nl = e >> 6, m = e & 63;
    const int n = o0 + nl;
    float s = 0.f;
    for (int z = 0; z < ks; z++)
      s += P[(((size_t)z * BB + b) * 512 + n) * 64 + m];
    tile[nl * 65 + m] = s * sval[m] + bias[n];
  }
  __syncthreads();
  for (int e = threadIdx.x; e < 4096; e += 256) {
    const int m = e >> 6, nl = e & 63;
    Y[((size_t)(b * 64) + m) * rowStride + chOff + o0 + nl] =
        f2bf(tile[nl * 65 + m]);
  }
}

__global__ __launch_bounds__(256) void anchor_reduce_dual_kernel(
    const float* __restrict__ P1, const float* __restrict__ b_cp,
    const int* __restrict__ anchor, ushort* __restrict__ cat,
    const float* __restrict__ P0, const float* __restrict__ b_cp0,
    const int* __restrict__ frame_anchor, ushort* __restrict__ FconT) {
  __shared__ float tile[64 * 65];
  __shared__ float sval[64];
  if (blockIdx.z == 0)
    anchor_reduce_body(P1, 8, b_cp, anchor, 64, cat, CATP, 2546, tile, sval);
  else
    anchor_reduce_body(P0, 4, b_cp0, frame_anchor, 256, FconT, 512, 0, tile, sval);
}

extern "C" void kernel_launch(void* const* d_in, const int* in_sizes, int n_in,
                              void* d_out, int out_size, void* d_ws,
                              size_t ws_size, hipStream_t stream) {
  const float* feature      = (const float*)d_in[0];
  const float* frame_feat   = (const float*)d_in[1];
  const int*   segments     = (const int*)d_in[2];
  const int*   frame_segs   = (const int*)d_in[3];
  const float* feat_lastcls = (const float*)d_in[4];
  const int*   anchor       = (const int*)d_in[5];
  const int*   frame_anchor = (const int*)d_in[6];
  const float* locres       = (const float*)d_in[8];
  const float* w_cur  = (const float*)d_in[9];
  const float* b_cur  = (const float*)d_in[10];
  const float* g_cur  = (const float*)d_in[11];
  const float* be_cur = (const float*)d_in[12];
  const float* w_lr   = (const float*)d_in[13];
  const float* b_lr   = (const float*)d_in[14];
  const float* g_lr   = (const float*)d_in[15];
  const float* be_lr  = (const float*)d_in[16];
  const float* w_roi  = (const float*)d_in[17];
  const float* b_roi  = (const float*)d_in[18];
  const float* g_roi  = (const float*)d_in[19];
  const float* be_roi = (const float*)d_in[20];
  const float* w_cp   = (const float*)d_in[21];  // [512,1024,16]
  const float* b_cp   = (const float*)d_in[22];
  const float* w_cp0  = (const float*)d_in[23];  // [512,512,8]
  const float* b_cp0  = (const float*)d_in[24];
  const float* w_prop = (const float*)d_in[25];  // [512,3572]
  const float* b_prop = (const float*)d_in[26];
  const float* g_prop = (const float*)d_in[27];
  const float* be_prop= (const float*)d_in[28];

  float* out_main = (float*)d_out;                  // [8,512,64]
  float* feat_lr  = (float*)d_out + BB * 512 * 64;  // [8,1024,64]

  // workspace layout (ushort units)
  ushort* cat_t  = (ushort*)d_ws;             // 1,835,008
  ushort* Ft     = cat_t + 1835008;           // 262,144
  ushort* XbmpT  = Ft + 262144;               // 262,144
  ushort* FconT  = XbmpT + 262144;            // 262,144
  ushort* Wcomb  = FconT + 262144;            // 786,432 (frag, 24 o-tiles K512)
  ushort* Wroi   = Wcomb + 786432;            // 262,144 (frag)
  ushort* Wprop  = Wroi + 262144;             // 1,835,008 (frag, K3584)
  ushort* WcpT   = Wprop + 1835008;           // 8,388,608 (frag)
  ushort* Wcp0T  = WcpT + 8388608;            // 2,097,152 (frag)
  ushort* FlrT   = Wcp0T + 2097152;           // 524,288  [8*64][1024]
  ushort* FfT    = FlrT + 524288;             // 1,048,576 [8*256][512]
  float*  P1     = (float*)(FfT + 1048576);   // 2,097,152 f (8 slices)
  float*  P0     = P1 + 2097152;              // 1,048,576 f (4 slices)
  // total ~47.7 MB

  // L1: dense weight fragment converts
  cvt_wfrag_kernel<<<1408, 256, 0, stream>>>(
      w_cur, w_lr, w_roi, w_prop, Wcomb, Wroi, Wprop);

  // L2: anchor conv weight fragment converts
  cvt_cpT_kernel<<<1024, 256, 0, stream>>>(w_cp, WcpT, w_cp0, Wcp0T);

  // L3: activation transposes (+ lastcls & locres into cat)
  transpose_multi_kernel<<<392, 256, 0, stream>>>(
      feature, frame_feat, feat_lastcls, locres, Ft, FfT, cat_t);

  // L4: fm_short -> cat[1536:2048]  |  feat_lr -> out + FlrT
  gemm_gn_seg_kernel<<<dim3(24, BB), 256, 0, stream>>>(
      8,
      Ft, Wcomb, b_cur, g_cur, be_cur, 512, 4, nullptr, 0, cat_t, CATP, 1536,
      Ft, Wcomb + 512 * 512, b_lr, g_lr, be_lr, 512, 5, feat_lr, 1024, FlrT,
      1024, 0);

  // L5: prop_feature -> cat[512:1536]  |  bmp(frame) -> XbmpT
  bmp_dual_kernel<<<dim3(64, BB, 2), 256, 0, stream>>>(
      FlrT, segments, cat_t, FfT, frame_segs, XbmpT);

  // L6: both anchor convs (fused gather) -> P1 / P0
  anchor_mfma_dual_kernel<<<dim3(8, BB, 12), 256, 0, stream>>>(
      FlrT, anchor, WcpT, P1, FfT, frame_anchor, Wcp0T, P0);

  // L7: split-K reduce -> cat[2546:3058] | FconT
  anchor_reduce_dual_kernel<<<dim3(8, BB, 2), 256, 0, stream>>>(
      P1, b_cp, anchor, cat_t, P0, b_cp0, frame_anchor, FconT);

  // L8: prop_roi -> cat[0:512]  |  prop_con -> cat[3058:3570]
  gemm_gn_seg_kernel<<<dim3(16, BB), 256, 0, stream>>>(
      8,
      XbmpT, Wroi, b_roi, g_roi, be_roi, 512, 4, nullptr, 0, cat_t, CATP, 0,
      FconT, Wroi, b_roi, g_roi, be_roi, 512, 4, nullptr, 0, cat_t, CATP, 3058);

  // L9: final projection -> out_main
  gemm_gn_seg_kernel<<<dim3(8, BB), 256, 0, stream>>>(
      8,
      cat_t, Wprop, b_prop, g_prop, be_prop, CATP, 4, out_main, 512, nullptr,
      CATP, 0,
      cat_t, Wprop, b_prop, g_prop, be_prop, CATP, 4, nullptr, 0, nullptr,
      CATP, 0);
}

// Round 8
// 266.671 us; speedup vs baseline: 1.7356x; 1.1573x over previous
//
#include <hip/hip_runtime.h>
#include <math.h>

#define BB 8
#define CATP 3584   // padded cat K (3572 -> 3584, zeros)
#define CAT_REAL 3572

typedef __attribute__((ext_vector_type(8))) short short8;
typedef __attribute__((ext_vector_type(4))) float f32x4;

__device__ inline ushort f2bf(float f) {
  union { float f; unsigned u; } x;
  x.f = f;
  return (ushort)((x.u + 0x7FFFu + ((x.u >> 16) & 1u)) >> 16);
}
__device__ inline float bf2f(unsigned us) {
  union { unsigned u; float f; } x;
  x.u = us << 16;
  return x.f;
}

// ---------------------------------------------------------------------------
// PREP (one launch): dense weight frags + anchor conv weight frags + all
// activation transposes.
// blocks [0,1408): dense weights -> MFMA fragment order
//   frag layout (shorts): (((ot*(Kp/32)+kc)*4+i)*64 + l4*16+l15)*8 + kk
// blocks [1408,1792): w_cp/w_cp0 [O][C][K] -> fragment order
//   (((nt*Kf+k)*(Cin/32)+cc))*2048 + tid*8  (tid = j*64+l4*16+l15)
//   Thread reads full 64B k-line of 8 c-rows (registers), writes 16B/k —
//   per-wave 1KB contiguous bursts, no LDS.
// blocks [1792,2184): activation transposes into Ft / FfT / cat.
// ---------------------------------------------------------------------------
template <int Cin, int Kf>
__device__ void cpT_tile(const float* __restrict__ W, ushort* __restrict__ D,
                         int nt, int cc) {
  const int tid = threadIdx.x;
  const int j = tid >> 6, l4 = (tid >> 4) & 3, l15 = tid & 15;
  const int o = nt * 64 + j * 16 + l15;
  const int cb = cc * 32 + l4 * 8;
  ushort rg[8][Kf];
#pragma unroll
  for (int q = 0; q < 8; q++) {
    const float* row = W + ((size_t)o * Cin + cb + q) * Kf;
#pragma unroll
    for (int kq = 0; kq < Kf / 4; kq++) {
      const float4 f = *(const float4*)(row + kq * 4);
      rg[q][kq * 4 + 0] = f2bf(f.x);
      rg[q][kq * 4 + 1] = f2bf(f.y);
      rg[q][kq * 4 + 2] = f2bf(f.z);
      rg[q][kq * 4 + 3] = f2bf(f.w);
    }
  }
#pragma unroll
  for (int k = 0; k < Kf; k++) {
    uint4 pk;
    pk.x = (unsigned)rg[0][k] | ((unsigned)rg[1][k] << 16);
    pk.y = (unsigned)rg[2][k] | ((unsigned)rg[3][k] << 16);
    pk.z = (unsigned)rg[4][k] | ((unsigned)rg[5][k] << 16);
    pk.w = (unsigned)rg[6][k] | ((unsigned)rg[7][k] << 16);
    *(uint4*)(D + ((size_t)(nt * Kf + k) * (Cin >> 5) + cc) * 2048 + tid * 8) = pk;
  }
}

__global__ __launch_bounds__(256) void prep_kernel(
    const float* __restrict__ w_cur, const float* __restrict__ w_lr,
    const float* __restrict__ w_roi, const float* __restrict__ w_prop,
    ushort* __restrict__ Wcomb, ushort* __restrict__ Wroi,
    ushort* __restrict__ Wprop, const float* __restrict__ w_cp,
    ushort* __restrict__ WcpT, const float* __restrict__ w_cp0,
    ushort* __restrict__ Wcp0T, const float* __restrict__ feature,
    const float* __restrict__ frame_feat, const float* __restrict__ lastcls,
    const float* __restrict__ locres, ushort* __restrict__ Ft,
    ushort* __restrict__ FfT, ushort* __restrict__ cat) {
  __shared__ float tile[64 * 65];
  const int bid = blockIdx.x;
  if (bid < 1408) {
    // --- dense weight fragment convert ---
    const int i = bid * 256 + threadIdx.x;
    const float* src;
    ushort* dst;
    int o, k8, Kc;
    bool pad = false;
    if (i < 98304) {
      o = i >> 6; k8 = i & 63; Kc = 16;
      src = (o < 512) ? (w_cur + (size_t)o * 512)
                      : (w_lr + (size_t)(o - 512) * 512);
      dst = Wcomb;
    } else if (i < 131072) {
      const int r = i - 98304;
      o = r >> 6; k8 = r & 63; Kc = 16;
      src = w_roi + (size_t)o * 512;
      dst = Wroi;
    } else {
      const int r = i - 131072;
      if (r >= 229376) return;
      o = r / 448; k8 = r % 448; Kc = 112;
      src = w_prop + (size_t)o * CAT_REAL;
      dst = Wprop;
      pad = true;
    }
    const int k = k8 * 8;
    float v[8];
    if (pad) {
#pragma unroll
      for (int q = 0; q < 8; q++) v[q] = (k + q < CAT_REAL) ? src[k + q] : 0.f;
    } else {
      const float4 f0 = *(const float4*)(src + k);
      const float4 f1 = *(const float4*)(src + k + 4);
      v[0] = f0.x; v[1] = f0.y; v[2] = f0.z; v[3] = f0.w;
      v[4] = f1.x; v[5] = f1.y; v[6] = f1.z; v[7] = f1.w;
    }
    uint4 pk;
    pk.x = (unsigned)f2bf(v[0]) | ((unsigned)f2bf(v[1]) << 16);
    pk.y = (unsigned)f2bf(v[2]) | ((unsigned)f2bf(v[3]) << 16);
    pk.z = (unsigned)f2bf(v[4]) | ((unsigned)f2bf(v[5]) << 16);
    pk.w = (unsigned)f2bf(v[6]) | ((unsigned)f2bf(v[7]) << 16);
    const int ot = o >> 6, ii = (o >> 4) & 3, l15 = o & 15;
    const int kc = k8 >> 2, l4 = k8 & 3;
    const size_t flat =
        ((((size_t)ot * Kc + kc) * 4 + ii) * 64 + l4 * 16 + l15) * 8;
    *(uint4*)(dst + flat) = pk;
    return;
  }
  if (bid < 1792) {
    const int local = bid - 1408;
    if (local < 256)
      cpT_tile<1024, 16>(w_cp, WcpT, local >> 5, local & 31);
    else {
      const int r = local - 256;
      cpT_tile<512, 8>(w_cp0, Wcp0T, r >> 4, r & 15);
    }
    return;
  }
  // --- activation transposes ---
  const int local = bid - 1792;
  const float* src;
  ushort* dst;
  int Cr, Cw, L, rs, co, cblk, lblk, b;
  if (local < 64) {
    src = feature; dst = Ft; Cr = 512; Cw = 512; L = 64; rs = 512; co = 0;
    cblk = local & 7; lblk = 0; b = local >> 3;
  } else if (local < 320) {
    const int r = local - 64;
    src = frame_feat; dst = FfT; Cr = 512; Cw = 512; L = 256; rs = 512; co = 0;
    cblk = r & 7; lblk = (r >> 3) & 3; b = r >> 5;
  } else if (local < 384) {
    const int r = local - 320;
    src = lastcls; dst = cat; Cr = 498; Cw = 498; L = 64; rs = CATP; co = 2048;
    cblk = r & 7; lblk = 0; b = r >> 3;
  } else {
    const int r = local - 384;
    src = locres; dst = cat; Cr = 2; Cw = 14; L = 64; rs = CATP; co = 3570;
    cblk = 0; lblk = 0; b = r;
  }
  const int c0 = cblk * 64, l0 = lblk * 64;
  for (int e = threadIdx.x; e < 4096; e += 256) {
    const int cc = e >> 6, ll = e & 63;
    const int c = c0 + cc;
    tile[cc * 65 + ll] = (c < Cr) ? src[((size_t)b * Cr + c) * L + l0 + ll] : 0.f;
  }
  __syncthreads();
  for (int e = threadIdx.x; e < 4096; e += 256) {
    const int ll = e >> 6, cc = e & 63;
    const int c = c0 + cc;
    if (c < Cw)
      dst[((size_t)b * L + l0 + ll) * rs + co + c] = f2bf(tile[cc * 65 + ll]);
  }
}

// ---------------------------------------------------------------------------
// Two-segment fused bf16 MFMA GEMM + GroupNorm + ReLU (frag-order weights).
// ---------------------------------------------------------------------------
__global__ __launch_bounds__(256) void gemm_gn_seg_kernel(
    int nblk0,
    const ushort* __restrict__ X0, const ushort* __restrict__ W0,
    const float* __restrict__ b0, const float* __restrict__ g0,
    const float* __restrict__ e0, int Kp0, int cs0, float* of0, int om0,
    ushort* co0, int cst0, int coff0,
    const ushort* __restrict__ X1, const ushort* __restrict__ W1,
    const float* __restrict__ b1, const float* __restrict__ g1,
    const float* __restrict__ e1, int Kp1, int cs1, float* of1, int om1,
    ushort* co1, int cst1, int coff1) {
  const int bx = blockIdx.x;
  const bool s1 = bx >= nblk0;
  const ushort* Xt = s1 ? X1 : X0;
  const ushort* Wb = s1 ? W1 : W0;
  const float* bias = s1 ? b1 : b0;
  const float* gamma = s1 ? g1 : g0;
  const float* beta = s1 ? e1 : e0;
  const int Kp = s1 ? Kp1 : Kp0;
  const int cpgShift = s1 ? cs1 : cs0;
  float* outF = s1 ? of1 : of0;
  const int outFM = s1 ? om1 : om0;
  ushort* catOut = s1 ? co1 : co0;
  const int catStride = s1 ? cst1 : cst0;
  const int chOff = s1 ? coff1 : coff0;
  const int o0 = (s1 ? bx - nblk0 : bx) * 64;

  const int b = blockIdx.y;
  const int w = threadIdx.x >> 6;
  const int lane = threadIdx.x & 63;
  const int l15 = lane & 15, l4 = lane >> 4;
  const int wk = Kp >> 2;
  const int kbeg = w * wk, kend = kbeg + wk;

  f32x4 acc[4][4] = {};
  const ushort* wbase = Wb + (size_t)(o0 >> 6) * (Kp >> 5) * 2048 + lane * 8;
  const ushort* bp[4];
#pragma unroll
  for (int j = 0; j < 4; j++)
    bp[j] = Xt + (size_t)(b * 64 + j * 16 + l15) * Kp + l4 * 8;

  for (int k = kbeg; k < kend; k += 32) {
    const int kc = k >> 5;
    short8 a[4], x[4];
#pragma unroll
    for (int i = 0; i < 4; i++)
      a[i] = *(const short8*)(wbase + ((size_t)kc * 4 + i) * 512);
#pragma unroll
    for (int j = 0; j < 4; j++) x[j] = *(const short8*)(bp[j] + k);
#pragma unroll
    for (int i = 0; i < 4; i++)
#pragma unroll
      for (int j = 0; j < 4; j++)
        acc[i][j] = __builtin_amdgcn_mfma_f32_16x16x32_bf16(a[i], x[j],
                                                            acc[i][j], 0, 0, 0);
  }

  __shared__ float red[64 * 65];
  for (int ww = 0; ww < 4; ww++) {
    __syncthreads();
    if (w == ww) {
#pragma unroll
      for (int i = 0; i < 4; i++)
#pragma unroll
        for (int j = 0; j < 4; j++)
#pragma unroll
          for (int r = 0; r < 4; r++) {
            const int m = i * 16 + l4 * 4 + r;
            const int n = j * 16 + l15;
            if (ww == 0)
              red[m * 65 + n] = acc[i][j][r] + bias[o0 + m];
            else
              red[m * 65 + n] += acc[i][j][r];
          }
    }
  }
  __syncthreads();

  const int cpg = 1 << cpgShift;
  const int ngroups = 64 >> cpgShift;
  __shared__ float rs[4], rss[4], gmean[4], grstd[4];
  for (int gi = 0; gi < ngroups; gi++) {
    float s = 0.f, ss = 0.f;
    const int nel = cpg << 6;
    for (int e = threadIdx.x; e < nel; e += 256) {
      const float v = red[((gi << cpgShift) + (e >> 6)) * 65 + (e & 63)];
      s += v;
      ss += v * v;
    }
#pragma unroll
    for (int off = 32; off > 0; off >>= 1) {
      s += __shfl_down(s, off);
      ss += __shfl_down(ss, off);
    }
    if (lane == 0) { rs[w] = s; rss[w] = ss; }
    __syncthreads();
    if (threadIdx.x == 0) {
      const float ts = rs[0] + rs[1] + rs[2] + rs[3];
      const float tss = rss[0] + rss[1] + rss[2] + rss[3];
      const float mean = ts / (float)nel;
      const float var = tss / (float)nel - mean * mean;
      gmean[gi] = mean;
      grstd[gi] = rsqrtf(var + 1e-5f);
    }
    __syncthreads();
  }

  if (outF) {
    for (int e = threadIdx.x; e < 4096; e += 256) {
      const int m = e >> 6, n = e & 63;
      const int gi = m >> cpgShift;
      const int c = o0 + m;
      float v = (red[m * 65 + n] - gmean[gi]) * grstd[gi] * gamma[c] + beta[c];
      v = fmaxf(v, 0.f);
      outF[((size_t)b * outFM + c) * 64 + n] = v;
    }
  }
  if (catOut) {
    for (int e = threadIdx.x; e < 4096; e += 256) {
      const int n = e >> 6, m = e & 63;
      const int gi = m >> cpgShift;
      const int c = o0 + m;
      float v = (red[m * 65 + n] - gmean[gi]) * grstd[gi] * gamma[c] + beta[c];
      v = fmaxf(v, 0.f);
      catOut[((size_t)(b * 64) + n) * catStride + chOff + c] = f2bf(v);
    }
  }
}

// ---------------------------------------------------------------------------
// Final projection split-K partials: P9[(kz*8+b)*512 + o][t], grid (8,8,4).
// ---------------------------------------------------------------------------
__global__ __launch_bounds__(256) void gemm_part_kernel(
    const ushort* __restrict__ Xt, const ushort* __restrict__ Wb,
    float* __restrict__ P) {
  const int ot = blockIdx.x;
  const int b = blockIdx.y;
  const int kz = blockIdx.z;
  const int w = threadIdx.x >> 6;
  const int lane = threadIdx.x & 63;
  const int l15 = lane & 15, l4 = lane >> 4;
  const int kbeg = kz * 896 + w * 224;
  const int kend = kbeg + 224;

  f32x4 acc[4][4] = {};
  const ushort* wbase = Wb + (size_t)ot * (CATP >> 5) * 2048 + lane * 8;
  const ushort* bp[4];
#pragma unroll
  for (int j = 0; j < 4; j++)
    bp[j] = Xt + (size_t)(b * 64 + j * 16 + l15) * CATP + l4 * 8;

  for (int k = kbeg; k < kend; k += 32) {
    const int kc = k >> 5;
    short8 a[4], x[4];
#pragma unroll
    for (int i = 0; i < 4; i++)
      a[i] = *(const short8*)(wbase + ((size_t)kc * 4 + i) * 512);
#pragma unroll
    for (int j = 0; j < 4; j++) x[j] = *(const short8*)(bp[j] + k);
#pragma unroll
    for (int i = 0; i < 4; i++)
#pragma unroll
      for (int j = 0; j < 4; j++)
        acc[i][j] = __builtin_amdgcn_mfma_f32_16x16x32_bf16(a[i], x[j],
                                                            acc[i][j], 0, 0, 0);
  }

  __shared__ float red[64 * 65];
  for (int ww = 0; ww < 4; ww++) {
    __syncthreads();
    if (w == ww) {
#pragma unroll
      for (int i = 0; i < 4; i++)
#pragma unroll
        for (int j = 0; j < 4; j++)
#pragma unroll
          for (int r = 0; r < 4; r++) {
            const int m = i * 16 + l4 * 4 + r;
            const int n = j * 16 + l15;
            if (ww == 0)
              red[m * 65 + n] = acc[i][j][r];
            else
              red[m * 65 + n] += acc[i][j][r];
          }
    }
  }
  __syncthreads();
  float* Pp = P + (((size_t)kz * BB + b) * 512 + ot * 64) * 64;
  for (int e = threadIdx.x; e < 4096; e += 256) Pp[e] = red[(e >> 6) * 65 + (e & 63)];
}

// ---------------------------------------------------------------------------
// Final projection reduce + bias + GN + ReLU -> out_main f32. grid (8,8).
// ---------------------------------------------------------------------------
__global__ __launch_bounds__(256) void reduce_gn_kernel(
    const float* __restrict__ P, const float* __restrict__ bias,
    const float* __restrict__ gamma, const float* __restrict__ beta,
    float* __restrict__ outF) {
  const int ot = blockIdx.x;
  const int b = blockIdx.y;
  const int o0 = ot * 64;
  const int w = threadIdx.x >> 6;
  const int lane = threadIdx.x & 63;
  __shared__ float red[64 * 65];
  for (int e = threadIdx.x; e < 4096; e += 256) {
    const int m = e >> 6, n = e & 63;
    float s = bias[o0 + m];
#pragma unroll
    for (int z = 0; z < 4; z++)
      s += P[(((size_t)z * BB + b) * 512 + o0 + m) * 64 + n];
    red[m * 65 + n] = s;
  }
  __syncthreads();
  __shared__ float rs[4], rss[4], gmean[4], grstd[4];
  for (int gi = 0; gi < 4; gi++) {
    float s = 0.f, ss = 0.f;
    for (int e = threadIdx.x; e < 1024; e += 256) {
      const float v = red[((gi << 4) + (e >> 6)) * 65 + (e & 63)];
      s += v;
      ss += v * v;
    }
#pragma unroll
    for (int off = 32; off > 0; off >>= 1) {
      s += __shfl_down(s, off);
      ss += __shfl_down(ss, off);
    }
    if (lane == 0) { rs[w] = s; rss[w] = ss; }
    __syncthreads();
    if (threadIdx.x == 0) {
      const float ts = rs[0] + rs[1] + rs[2] + rs[3];
      const float tss = rss[0] + rss[1] + rss[2] + rss[3];
      const float mean = ts / 1024.f;
      const float var = tss / 1024.f - mean * mean;
      gmean[gi] = mean;
      grstd[gi] = rsqrtf(var + 1e-5f);
    }
    __syncthreads();
  }
  for (int e = threadIdx.x; e < 4096; e += 256) {
    const int m = e >> 6, n = e & 63;
    const int gi = m >> 4;
    const int c = o0 + m;
    float v = (red[m * 65 + n] - gmean[gi]) * grstd[gi] * gamma[c] + beta[c];
    outF[((size_t)b * 512 + c) * 64 + n] = fmaxf(v, 0.f);
  }
}

// ---------------------------------------------------------------------------
// Dual BoundaryMaxPooling on transposed bf16.
// ---------------------------------------------------------------------------
template <int C, int L>
__device__ void bmp_body(const ushort* __restrict__ Xt,
                         const int* __restrict__ segs, ushort* __restrict__ Y,
                         int rowStride, int chOff, float2 (*pmax)[512]) {
  constexpr int C2 = C / 2;
  constexpr int P2 = C2 / 2;
  constexpr int CH = P2 / 64;
  const int t = blockIdx.x;
  const int b = blockIdx.y;
  const int w = threadIdx.x >> 6;
  const int lane = threadIdx.x & 63;
  const int* sg = segs + ((size_t)b * 64 + t) * 4;
  const ushort* Xb = Xt + (size_t)b * L * C;
#pragma unroll
  for (int h = 0; h < 2; h++) {
    const int s = min(max(sg[2 * h], 0), L - 1);
    const int e = max(min(max(sg[2 * h + 1], 0), L - 1), s);
#pragma unroll
    for (int q = 0; q < CH; q++) {
      const int p = q * 64 + lane;
      const ushort* base = Xb + h * C2 + 2 * p;
      float a0 = -INFINITY, a1 = -INFINITY;
      float c0 = -INFINITY, c1 = -INFINITY;
      int l = s + w;
      for (; l + 4 <= e; l += 8) {
        const unsigned u0 = *(const unsigned*)(base + (size_t)l * C);
        const unsigned u1 = *(const unsigned*)(base + (size_t)(l + 4) * C);
        a0 = fmaxf(a0, bf2f(u0 & 0xffffu));
        a1 = fmaxf(a1, bf2f(u0 >> 16));
        c0 = fmaxf(c0, bf2f(u1 & 0xffffu));
        c1 = fmaxf(c1, bf2f(u1 >> 16));
      }
      if (l <= e) {
        const unsigned u0 = *(const unsigned*)(base + (size_t)l * C);
        a0 = fmaxf(a0, bf2f(u0 & 0xffffu));
        a1 = fmaxf(a1, bf2f(u0 >> 16));
      }
      pmax[w][h * P2 + p] = make_float2(fmaxf(a0, c0), fmaxf(a1, c1));
    }
  }
  __syncthreads();
  for (int idx = threadIdx.x; idx < 2 * P2; idx += 256) {
    float2 m = pmax[0][idx];
#pragma unroll
    for (int ww = 1; ww < 4; ww++) {
      const float2 v = pmax[ww][idx];
      m.x = fmaxf(m.x, v.x);
      m.y = fmaxf(m.y, v.y);
    }
    const unsigned o = (unsigned)f2bf(m.x) | ((unsigned)f2bf(m.y) << 16);
    *(unsigned*)(Y + ((size_t)(b * 64) + t) * rowStride + chOff + 2 * idx) = o;
  }
}

__global__ __launch_bounds__(256) void bmp_dual_kernel(
    const ushort* __restrict__ FlrT, const int* __restrict__ segments,
    ushort* __restrict__ cat, const ushort* __restrict__ FfT,
    const int* __restrict__ frame_segs, ushort* __restrict__ XbmpT) {
  __shared__ float2 pm[4][512];
  if (blockIdx.z == 0)
    bmp_body<1024, 64>(FlrT, segments, cat, CATP, 512, pm);
  else
    bmp_body<512, 256>(FfT, frame_segs, XbmpT, 512, 0, pm);
}

// ---------------------------------------------------------------------------
// Dual anchor-conv MFMA, fused gather, frag-order weights, split-K + split-C.
// ---------------------------------------------------------------------------
template <int Kf, int L, int Cin>
__device__ void anchor_mfma_body(const ushort* __restrict__ src,
                                 const int* __restrict__ anc,
                                 const ushort* __restrict__ Wt,
                                 float* __restrict__ P, int slice, float* red) {
  const int nt = blockIdx.x;
  const int b = blockIdx.y;
  const int w = threadIdx.x >> 6;
  const int lane = threadIdx.x & 63;
  const int l15 = lane & 15, l4 = lane >> 4;
  const int kz = slice >> 1, chalf = slice & 1;
  const int k = kz * 4 + w;
  const int cbase = chalf * (Cin / 2);

  const ushort* rp[4];
#pragma unroll
  for (int i = 0; i < 4; i++) {
    const int t = i * 16 + l15;
    const int a0 = anc[((size_t)b * 64 + t) * 2 + 0];
    const int a1 = anc[((size_t)b * 64 + t) * 2 + 1];
    const int left = min(max(a0, 0), L);
    const int right = min(max(a1, 0), L);
    const int seglen = right + 1 - left;
    const int ix = min(max(left + (k * seglen) / Kf, 0), L - 1);
    rp[i] = src + ((size_t)b * L + ix) * Cin + cbase + l4 * 8;
  }
  const ushort* wb = Wt + (size_t)(nt * Kf + k) * (Cin >> 5) * 2048 + lane * 8;

  f32x4 acc[4][4] = {};
  for (int c0 = 0; c0 < Cin / 2; c0 += 32) {
    const int cc = (cbase + c0) >> 5;
    short8 a[4], bb[4];
#pragma unroll
    for (int i = 0; i < 4; i++) a[i] = *(const short8*)(rp[i] + c0);
#pragma unroll
    for (int j = 0; j < 4; j++)
      bb[j] = *(const short8*)(wb + ((size_t)cc * 4 + j) * 512);
#pragma unroll
    for (int i = 0; i < 4; i++)
#pragma unroll
      for (int j = 0; j < 4; j++)
        acc[i][j] = __builtin_amdgcn_mfma_f32_16x16x32_bf16(a[i], bb[j],
                                                            acc[i][j], 0, 0, 0);
  }

  for (int ww = 0; ww < 4; ww++) {
    __syncthreads();
    if (w == ww) {
#pragma unroll
      for (int i = 0; i < 4; i++)
#pragma unroll
        for (int j = 0; j < 4; j++)
#pragma unroll
          for (int r = 0; r < 4; r++) {
            const int m = i * 16 + l4 * 4 + r;
            const int n = j * 16 + l15;
            if (ww == 0)
              red[m * 65 + n] = acc[i][j][r];
            else
              red[m * 65 + n] += acc[i][j][r];
          }
    }
  }
  __syncthreads();
  float* Pp = P + (((size_t)slice * BB + b) * 512 + nt * 64) * 64;
  for (int e = threadIdx.x; e < 4096; e += 256) {
    const int n = e >> 6, m = e & 63;
    Pp[e] = red[m * 65 + n];
  }
}

__global__ __launch_bounds__(256) void anchor_mfma_dual_kernel(
    const ushort* __restrict__ FlrT, const int* __restrict__ anchor,
    const ushort* __restrict__ WcpT, float* __restrict__ P1,
    const ushort* __restrict__ FfT, const int* __restrict__ frame_anchor,
    const ushort* __restrict__ Wcp0T, float* __restrict__ P0) {
  __shared__ float red[64 * 65];
  const int z = blockIdx.z;
  if (z < 8)
    anchor_mfma_body<16, 64, 1024>(FlrT, anchor, WcpT, P1, z, red);
  else
    anchor_mfma_body<8, 256, 512>(FfT, frame_anchor, Wcp0T, P0, z - 8, red);
}

// ---------------------------------------------------------------------------
// Dual split-K reduce + valid mask + bias -> bf16 transposed rows.
// ---------------------------------------------------------------------------
__device__ void anchor_reduce_body(const float* __restrict__ P, int ks,
                                   const float* __restrict__ bias,
                                   const int* __restrict__ anc, int L,
                                   ushort* __restrict__ Y, int rowStride,
                                   int chOff, float* tile, float* sval) {
  const int o0 = blockIdx.x * 64;
  const int b = blockIdx.y;
  if (threadIdx.x < 64) {
    const int t = threadIdx.x;
    const int a0 = anc[((size_t)b * 64 + t) * 2 + 0];
    const int a1 = anc[((size_t)b * 64 + t) * 2 + 1];
    const int left = min(max(a0, 0), L);
    const int right = min(max(a1, 0), L);
    sval[t] = (right > left) ? 1.f : 0.f;
  }
  __syncthreads();
  for (int e = threadIdx.x; e < 4096; e += 256) {
    const int nl = e >> 6, m = e & 63;
    const int n = o0 + nl;
    float s = 0.f;
    for (int z = 0; z < ks; z++)
      s += P[(((size_t)z * BB + b) * 512 + n) * 64 + m];
    tile[nl * 65 + m] = s * sval[m] + bias[n];
  }
  __syncthreads();
  for (int e = threadIdx.x; e < 4096; e += 256) {
    const int m = e >> 6, nl = e & 63;
    Y[((size_t)(b * 64) + m) * rowStride + chOff + o0 + nl] =
        f2bf(tile[nl * 65 + m]);
  }
}

__global__ __launch_bounds__(256) void anchor_reduce_dual_kernel(
    const float* __restrict__ P1, const float* __restrict__ b_cp,
    const int* __restrict__ anchor, ushort* __restrict__ cat,
    const float* __restrict__ P0, const float* __restrict__ b_cp0,
    const int* __restrict__ frame_anchor, ushort* __restrict__ FconT) {
  __shared__ float tile[64 * 65];
  __shared__ float sval[64];
  if (blockIdx.z == 0)
    anchor_reduce_body(P1, 8, b_cp, anchor, 64, cat, CATP, 2546, tile, sval);
  else
    anchor_reduce_body(P0, 4, b_cp0, frame_anchor, 256, FconT, 512, 0, tile, sval);
}

extern "C" void kernel_launch(void* const* d_in, const int* in_sizes, int n_in,
                              void* d_out, int out_size, void* d_ws,
                              size_t ws_size, hipStream_t stream) {
  const float* feature      = (const float*)d_in[0];
  const float* frame_feat   = (const float*)d_in[1];
  const int*   segments     = (const int*)d_in[2];
  const int*   frame_segs   = (const int*)d_in[3];
  const float* feat_lastcls = (const float*)d_in[4];
  const int*   anchor       = (const int*)d_in[5];
  const int*   frame_anchor = (const int*)d_in[6];
  const float* locres       = (const float*)d_in[8];
  const float* w_cur  = (const float*)d_in[9];
  const float* b_cur  = (const float*)d_in[10];
  const float* g_cur  = (const float*)d_in[11];
  const float* be_cur = (const float*)d_in[12];
  const float* w_lr   = (const float*)d_in[13];
  const float* b_lr   = (const float*)d_in[14];
  const float* g_lr   = (const float*)d_in[15];
  const float* be_lr  = (const float*)d_in[16];
  const float* w_roi  = (const float*)d_in[17];
  const float* b_roi  = (const float*)d_in[18];
  const float* g_roi  = (const float*)d_in[19];
  const float* be_roi = (const float*)d_in[20];
  const float* w_cp   = (const float*)d_in[21];  // [512,1024,16]
  const float* b_cp   = (const float*)d_in[22];
  const float* w_cp0  = (const float*)d_in[23];  // [512,512,8]
  const float* b_cp0  = (const float*)d_in[24];
  const float* w_prop = (const float*)d_in[25];  // [512,3572]
  const float* b_prop = (const float*)d_in[26];
  const float* g_prop = (const float*)d_in[27];
  const float* be_prop= (const float*)d_in[28];

  float* out_main = (float*)d_out;                  // [8,512,64]
  float* feat_lr  = (float*)d_out + BB * 512 * 64;  // [8,1024,64]

  // workspace layout (ushort units)
  ushort* cat_t  = (ushort*)d_ws;             // 1,835,008
  ushort* Ft     = cat_t + 1835008;           // 262,144
  ushort* XbmpT  = Ft + 262144;               // 262,144
  ushort* FconT  = XbmpT + 262144;            // 262,144
  ushort* Wcomb  = FconT + 262144;            // 786,432 (frag)
  ushort* Wroi   = Wcomb + 786432;            // 262,144 (frag)
  ushort* Wprop  = Wroi + 262144;             // 1,835,008 (frag)
  ushort* WcpT   = Wprop + 1835008;           // 8,388,608 (frag)
  ushort* Wcp0T  = WcpT + 8388608;            // 2,097,152 (frag)
  ushort* FlrT   = Wcp0T + 2097152;           // 524,288  [8*64][1024]
  ushort* FfT    = FlrT + 524288;             // 1,048,576 [8*256][512]
  float*  P1     = (float*)(FfT + 1048576);   // 2,097,152 f (8 slices)
  float*  P0     = P1 + 2097152;              // 1,048,576 f (4 slices)
  float*  P9     = P0 + 1048576;              // 1,048,576 f (4 slices)
  // total ~51.9 MB

  // L1: all weight converts + activation transposes (one launch)
  prep_kernel<<<2184, 256, 0, stream>>>(
      w_cur, w_lr, w_roi, w_prop, Wcomb, Wroi, Wprop, w_cp, WcpT, w_cp0,
      Wcp0T, feature, frame_feat, feat_lastcls, locres, Ft, FfT, cat_t);

  // L2: fm_short -> cat[1536:2048]  |  feat_lr -> out + FlrT
  gemm_gn_seg_kernel<<<dim3(24, BB), 256, 0, stream>>>(
      8,
      Ft, Wcomb, b_cur, g_cur, be_cur, 512, 4, nullptr, 0, cat_t, CATP, 1536,
      Ft, Wcomb + 512 * 512, b_lr, g_lr, be_lr, 512, 5, feat_lr, 1024, FlrT,
      1024, 0);

  // L3: prop_feature -> cat[512:1536]  |  bmp(frame) -> XbmpT
  bmp_dual_kernel<<<dim3(64, BB, 2), 256, 0, stream>>>(
      FlrT, segments, cat_t, FfT, frame_segs, XbmpT);

  // L4: both anchor convs (fused gather) -> P1 / P0
  anchor_mfma_dual_kernel<<<dim3(8, BB, 12), 256, 0, stream>>>(
      FlrT, anchor, WcpT, P1, FfT, frame_anchor, Wcp0T, P0);

  // L5: split-K reduce -> cat[2546:3058] | FconT
  anchor_reduce_dual_kernel<<<dim3(8, BB, 2), 256, 0, stream>>>(
      P1, b_cp, anchor, cat_t, P0, b_cp0, frame_anchor, FconT);

  // L6: prop_roi -> cat[0:512]  |  prop_con -> cat[3058:3570]
  gemm_gn_seg_kernel<<<dim3(16, BB), 256, 0, stream>>>(
      8,
      XbmpT, Wroi, b_roi, g_roi, be_roi, 512, 4, nullptr, 0, cat_t, CATP, 0,
      FconT, Wroi, b_roi, g_roi, be_roi, 512, 4, nullptr, 0, cat_t, CATP, 3058);

  // L7: final projection partials (split-K, 256 blocks)
  gemm_part_kernel<<<dim3(8, BB, 4), 256, 0, stream>>>(cat_t, Wprop, P9);

  // L8: reduce + bias + GN + ReLU -> out_main
  reduce_gn_kernel<<<dim3(8, BB), 256, 0, stream>>>(
      P9, b_prop, g_prop, be_prop, out_main);
}